// Round 16
// baseline (459.708 us; speedup 1.0000x reference)
//
#include <hip/hip_runtime.h>
#include <stdint.h>

typedef unsigned short u16;
typedef __attribute__((ext_vector_type(8))) short short8;
typedef __attribute__((ext_vector_type(4))) float f32x4;
typedef __attribute__((ext_vector_type(4))) unsigned short u16x4;

constexpr int CB = 4, CS = 1024, CD = 3584, CN = 28, CK = 4, CH = 128, CG = 7;
constexpr int CT = CB * CS;                    // 4096 tokens
constexpr int QKVC = CN * CH + 2 * CK * CH;    // 4608 fused qkv cols
constexpr long KV_HALF = (long)CB * CS * CK * CH; // 2,097,152 floats per cache half

__device__ __forceinline__ u16 f2bf(float f) {
  union { float f; uint32_t u; } c; c.f = f;
  uint32_t u = c.u + 0x7fffu + ((c.u >> 16) & 1);   // RNE to bf16
  return (u16)(u >> 16);
}

// async global->LDS, 16B per lane; LDS dest must be wave-uniform base (+lane*16 implicit)
__device__ __forceinline__ void gload16(const void* g, void* l) {
  __builtin_amdgcn_global_load_lds(
      (const __attribute__((address_space(1))) unsigned int*)(uintptr_t)g,
      (__attribute__((address_space(3))) unsigned int*)(uint32_t)(uintptr_t)l,
      16, 0, 0);
}

// ---------------- f32 [T][D] -> bf16 K-blocked [D/32][T][32] ----------------
__global__ __launch_bounds__(256) void cvt_blk_kernel(const float* __restrict__ in,
                                                      u16* __restrict__ outp, long n) {
  long i = ((long)blockIdx.x * 256 + threadIdx.x) * 4;
  if (i < n) {
    const float4 v = *(const float4*)(in + i);
    const int t = (int)(i / CD), d = (int)(i % CD);
    u16x4 o; o.x = f2bf(v.x); o.y = f2bf(v.y); o.z = f2bf(v.z); o.w = f2bf(v.w);
    *(u16x4*)(outp + ((long)(d >> 5) * CT + t) * 32 + (d & 31)) = o;
  }
}

// ---- transpose f32 src[.][C] -> bf16 K-blocked dst[K/KBW][RT][KBW], KBW = 1<<KSH ----
template <int KSH>
__global__ __launch_bounds__(256) void transpose_cvt_kernel(const float* __restrict__ src,
                                                            u16* __restrict__ dst,
                                                            int C, int dstOff, int RT) {
  __shared__ float tile[32][33];
  const int c0 = blockIdx.x * 32, r0 = blockIdx.y * 32;
  const int tx = threadIdx.x, ty = threadIdx.y;
  constexpr int KBW = 1 << KSH;
#pragma unroll
  for (int i = ty; i < 32; i += 8)
    tile[i][tx] = src[(long)(r0 + i) * C + c0 + tx];
  __syncthreads();
  const int k = r0 + tx;
#pragma unroll
  for (int i = ty; i < 32; i += 8)
    dst[((long)(k >> KSH) * RT + dstOff + c0 + i) * KBW + (k & (KBW - 1))] = f2bf(tile[tx][i]);
}

// ---- staging helpers for K32-blocked [rows][32] units (QKV GEMM) ----
__device__ __forceinline__ void stage_A(u16* dst, const u16* srcTile, int w, int lane) {
  const int ci0 = (w << 7) + lane;        // 1024 chunks of 16B; 2 per thread
  const int ci1 = ci0 + 64;
  const int l0 = (ci0 & 3) ^ ((ci0 >> 3) & 3);
  const int l1 = (ci1 & 3) ^ ((ci1 >> 3) & 3);
  gload16(srcTile + ((ci0 >> 2) << 5) + (l0 << 3), dst + (w << 10));
  gload16(srcTile + ((ci1 >> 2) << 5) + (l1 << 3), dst + (w << 10) + 512);
}
__device__ __forceinline__ void stage_B(u16* dst, const u16* srcTile, int w, int lane) {
  const int ci = (w << 6) + lane;         // 512 chunks; 1 per thread
  const int l = (ci & 3) ^ ((ci >> 3) & 3);
  gload16(srcTile + ((ci >> 2) << 5) + (l << 3), dst + (w << 9));
}

// ---------------- QKV GEMM: 256x128, BK=32, triple-buffered (proven 862 TF state) ----------------
template <int ADD_BIAS>
__global__ __launch_bounds__(512, 4) void gemm256_kernel(const u16* __restrict__ Ablk,
                                                         const u16* __restrict__ Bblk,
                                                         float* __restrict__ C,
                                                         const float* __restrict__ bq,
                                                         const float* __restrict__ bk2,
                                                         const float* __restrict__ bv,
                                                         int Ncol, int Kd) {
  __shared__ u16 Al[3][8192];   // 3 x 16KB
  __shared__ u16 Bl[3][4096];   // 3 x 8KB
  const int tid = threadIdx.x;
  const int w = tid >> 6, lane = tid & 63;
  const int g = lane >> 4, r = lane & 15;
  const int gs = (g ^ ((r >> 1) & 3)) << 3;   // swizzled fragment column (u16 units)
  // XCD-cooperative mapping
  const int xcd = (int)blockIdx.x & 7, c = (int)blockIdx.x >> 3;
  const int bm = ((xcd << 1) + (c & 1)) << 8;
  const int bn = (c >> 1) << 7;
  const int wM = (w >> 1) * 64;   // 4 M-slots
  const int wN = (w & 1) * 64;    // 2 N-slots

  f32x4 acc[4][4];
#pragma unroll
  for (int mi = 0; mi < 4; ++mi)
#pragma unroll
    for (int ni = 0; ni < 4; ++ni) acc[mi][ni] = f32x4{0.f, 0.f, 0.f, 0.f};

#define ATILE(t) (Ablk + ((long)(t) * CT + bm) * 32)
#define BTILE(t) (Bblk + ((long)(t) * Ncol + bn) * 32)
  stage_A(&Al[0][0], ATILE(0), w, lane);
  stage_B(&Bl[0][0], BTILE(0), w, lane);
  stage_A(&Al[1][0], ATILE(1), w, lane);
  stage_B(&Bl[1][0], BTILE(1), w, lane);

  const int NT = Kd >> 5;
  for (int t = 0; t < NT; ++t) {
    const int p = t % 3;
    if (t + 2 < NT) {
      const int f = (t + 2) % 3;
      stage_A(&Al[f][0], ATILE(t + 2), w, lane);
      stage_B(&Bl[f][0], BTILE(t + 2), w, lane);
      asm volatile("s_waitcnt vmcnt(6)" ::: "memory");   // tile t landed; t+1,t+2 in flight
    } else if (t + 1 < NT) {
      asm volatile("s_waitcnt vmcnt(3)" ::: "memory");
    } else {
      asm volatile("s_waitcnt vmcnt(0)" ::: "memory");
    }
    __builtin_amdgcn_s_barrier();
    short8 af[4], bf[4];
#pragma unroll
    for (int mi = 0; mi < 4; ++mi)
      af[mi] = *(const short8*)&Al[p][(wM + mi * 16 + r) * 32 + gs];
#pragma unroll
    for (int ni = 0; ni < 4; ++ni)
      bf[ni] = *(const short8*)&Bl[p][(wN + ni * 16 + r) * 32 + gs];
    __builtin_amdgcn_s_setprio(1);
#pragma unroll
    for (int mi = 0; mi < 4; ++mi)
#pragma unroll
      for (int ni = 0; ni < 4; ++ni)
        acc[mi][ni] = __builtin_amdgcn_mfma_f32_16x16x32_bf16(af[mi], bf[ni], acc[mi][ni], 0, 0, 0);
    __builtin_amdgcn_s_setprio(0);
    asm volatile("s_waitcnt lgkmcnt(0)" ::: "memory");   // reads of buf p retired
    __builtin_amdgcn_s_barrier();                        // before buf p is re-staged
  }
#undef ATILE
#undef BTILE

#pragma unroll
  for (int mi = 0; mi < 4; ++mi) {
#pragma unroll
    for (int ni = 0; ni < 4; ++ni) {
      const int col = bn + wN + ni * 16 + r;
      float badd = 0.f;
      if (ADD_BIAS)
        badd = (col < CN * CH) ? bq[col]
             : (col < CN * CH + CK * CH) ? bk2[col - CN * CH]
                                         : bv[col - CN * CH - CK * CH];
#pragma unroll
      for (int j = 0; j < 4; ++j) {
        const int row = bm + wM + mi * 16 + g * 4 + j;
        C[(long)row * Ncol + col] = acc[mi][ni][j] + badd;
      }
    }
  }
}

// ---------------- O-proj GEMM: 256x256, BK=64, 4-phase-per-K-tile fine interleave ----------------
// Operands K64-blocked. LDS 128KB = [2 buf][2 half][128x64] x {A,B}; unit = 16KB contiguous.
// Iter t (buf p=t&1) stages tile t+1's units B0,B1,A0,A1 at phases P0..P3 into buf p^1
// (safe: iter t-1's last reads of p^1 retire at its P2 lgkmcnt(0)+barriers).
// P0 waits vmcnt(2): exactly tile t's 8 loads drained, B0(t+1) stays in flight.
// Each phase: {ds_read subtile || stage} -> barrier -> lgkm0 -> setprio+16 MFMA -> barrier.
// Swizzle: stored physical chunk q of row holds logical q^(row&7); read chunk (ks*4+g)^(r&7).
__device__ __forceinline__ void stage_U(u16* dst, const u16* srcTile, int w, int lane) {
#pragma unroll
  for (int j = 0; j < 2; ++j) {
    const int ci = (w * 2 + j) * 64 + lane;   // 1024 chunks of 16B in [128][64]
    const int row = ci >> 3;
    const int chl = (ci & 7) ^ (row & 7);
    gload16(srcTile + row * 64 + chl * 8, dst + (w * 2 + j) * 512);
  }
}

__global__ __launch_bounds__(512) void gemm_8ph_kernel(const u16* __restrict__ Ablk,
                                                       const u16* __restrict__ Bblk,
                                                       float* __restrict__ C,
                                                       int Ncol, int Kd) {
  __shared__ u16 Al[2][2][8192];   // [buf][half][128*64]  64KB
  __shared__ u16 Bl[2][2][8192];   // 64KB
  const int tid = threadIdx.x;
  const int w = tid >> 6, lane = tid & 63;
  const int g = lane >> 4, r = lane & 15;
  const int xcd = (int)blockIdx.x & 7, c = (int)blockIdx.x >> 3;
  const int bm = ((xcd << 1) + (c & 1)) << 8;   // 16 m-panels: XCD owns 2 (L2-resident)
  const int bn = (c >> 1) << 8;                 // 14 n-panels swept by all XCDs together
  const int wm = (w >> 2) << 7;    // 0 or 128
  const int wn = (w & 3) << 6;     // 0,64,128,192
  const int ah = wm >> 7;          // wave's A half (wave-constant)
  const int bh = wn >> 7;          // wave's B half (wave-constant)
  const int brow = wn & 127;       // wave's row base inside B half

  f32x4 acc[8][4];
#pragma unroll
  for (int mi = 0; mi < 8; ++mi)
#pragma unroll
    for (int ni = 0; ni < 4; ++ni) acc[mi][ni] = f32x4{0.f, 0.f, 0.f, 0.f};

#define ATL(t, h) (Ablk + ((long)(t) * CT + bm + (h) * 128) * 64)
#define BTL(t, h) (Bblk + ((long)(t) * Ncol + bn + (h) * 128) * 64)
#define CSW(ks) ((((ks) * 4 + g) ^ (r & 7)) << 3)

  // prologue: tile 0 (B units first: streamed -> need longest lead)
  stage_U(&Bl[0][0][0], BTL(0, 0), w, lane);
  stage_U(&Bl[0][1][0], BTL(0, 1), w, lane);
  stage_U(&Al[0][0][0], ATL(0, 0), w, lane);
  stage_U(&Al[0][1][0], ATL(0, 1), w, lane);

  const int NT = Kd >> 6;   // 56
  short8 af[4][2], bf0[2][2], bf1[2][2];
  for (int t = 0; t < NT; ++t) {
    const int p = t & 1;
    const bool pre = (t + 1 < NT);
    // ---------------- P0 ----------------
    if (pre) {
      stage_U(&Bl[p ^ 1][0][0], BTL(t + 1, 0), w, lane);
      asm volatile("s_waitcnt vmcnt(2)" ::: "memory");   // tile t fully landed
    } else {
      asm volatile("s_waitcnt vmcnt(0)" ::: "memory");
    }
    __builtin_amdgcn_s_barrier();
#pragma unroll
    for (int mi = 0; mi < 4; ++mi)
#pragma unroll
      for (int ks = 0; ks < 2; ++ks)
        af[mi][ks] = *(const short8*)&Al[p][ah][(mi * 16 + r) * 64 + CSW(ks)];
#pragma unroll
    for (int ni = 0; ni < 2; ++ni)
#pragma unroll
      for (int ks = 0; ks < 2; ++ks)
        bf0[ni][ks] = *(const short8*)&Bl[p][bh][(brow + ni * 16 + r) * 64 + CSW(ks)];
    asm volatile("s_waitcnt lgkmcnt(0)" ::: "memory");
    __builtin_amdgcn_s_setprio(1);
#pragma unroll
    for (int ks = 0; ks < 2; ++ks)
#pragma unroll
      for (int mi = 0; mi < 4; ++mi)
#pragma unroll
        for (int ni = 0; ni < 2; ++ni)
          acc[mi][ni] = __builtin_amdgcn_mfma_f32_16x16x32_bf16(af[mi][ks], bf0[ni][ks], acc[mi][ni], 0, 0, 0);
    __builtin_amdgcn_s_setprio(0);
    __builtin_amdgcn_s_barrier();
    // ---------------- P1 ----------------
#pragma unroll
    for (int ni = 0; ni < 2; ++ni)
#pragma unroll
      for (int ks = 0; ks < 2; ++ks)
        bf1[ni][ks] = *(const short8*)&Bl[p][bh][(brow + 32 + ni * 16 + r) * 64 + CSW(ks)];
    if (pre) stage_U(&Bl[p ^ 1][1][0], BTL(t + 1, 1), w, lane);
    asm volatile("s_waitcnt lgkmcnt(0)" ::: "memory");
    __builtin_amdgcn_s_barrier();
    __builtin_amdgcn_s_setprio(1);
#pragma unroll
    for (int ks = 0; ks < 2; ++ks)
#pragma unroll
      for (int mi = 0; mi < 4; ++mi)
#pragma unroll
        for (int ni = 0; ni < 2; ++ni)
          acc[mi][ni + 2] = __builtin_amdgcn_mfma_f32_16x16x32_bf16(af[mi][ks], bf1[ni][ks], acc[mi][ni + 2], 0, 0, 0);
    __builtin_amdgcn_s_setprio(0);
    __builtin_amdgcn_s_barrier();
    // ---------------- P2 ----------------
#pragma unroll
    for (int mi = 0; mi < 4; ++mi)
#pragma unroll
      for (int ks = 0; ks < 2; ++ks)
        af[mi][ks] = *(const short8*)&Al[p][ah][((64 + mi * 16) + r) * 64 + CSW(ks)];
    if (pre) stage_U(&Al[p ^ 1][0][0], ATL(t + 1, 0), w, lane);
    asm volatile("s_waitcnt lgkmcnt(0)" ::: "memory");
    __builtin_amdgcn_s_barrier();
    __builtin_amdgcn_s_setprio(1);
#pragma unroll
    for (int ks = 0; ks < 2; ++ks)
#pragma unroll
      for (int mi = 0; mi < 4; ++mi)
#pragma unroll
        for (int ni = 0; ni < 2; ++ni)
          acc[mi + 4][ni + 2] = __builtin_amdgcn_mfma_f32_16x16x32_bf16(af[mi][ks], bf1[ni][ks], acc[mi + 4][ni + 2], 0, 0, 0);
    __builtin_amdgcn_s_setprio(0);
    __builtin_amdgcn_s_barrier();
    // ---------------- P3 ----------------
    if (pre) stage_U(&Al[p ^ 1][1][0], ATL(t + 1, 1), w, lane);
    __builtin_amdgcn_s_barrier();
    __builtin_amdgcn_s_setprio(1);
#pragma unroll
    for (int ks = 0; ks < 2; ++ks)
#pragma unroll
      for (int mi = 0; mi < 4; ++mi)
#pragma unroll
        for (int ni = 0; ni < 2; ++ni)
          acc[mi + 4][ni] = __builtin_amdgcn_mfma_f32_16x16x32_bf16(af[mi][ks], bf0[ni][ks], acc[mi + 4][ni], 0, 0, 0);
    __builtin_amdgcn_s_setprio(0);
    __builtin_amdgcn_s_barrier();
  }
#undef ATL
#undef BTL
#undef CSW

#pragma unroll
  for (int mi = 0; mi < 8; ++mi)
#pragma unroll
    for (int ni = 0; ni < 4; ++ni) {
      const int col = bn + wn + ni * 16 + r;
#pragma unroll
      for (int j = 0; j < 4; ++j)
        C[(long)(bm + wm + mi * 16 + g * 4 + j) * Ncol + col] = acc[mi][ni][j];
    }
}

// ---------------- RoPE + scatter: q->bf16 (pre-scaled) [B][N][S][H], k->cache f32 + bf16 [B][K][S][H] ----------------
__global__ __launch_bounds__(256) void rope_scatter_kernel(const float* __restrict__ qkv,
                                                           const int* __restrict__ positions,
                                                           u16* __restrict__ qb,
                                                           u16* __restrict__ kb,
                                                           float* __restrict__ cacheK) {
  const int t = blockIdx.x;
  const int b = t / CS, s = t % CS;
  __shared__ float csv[64], snv[64];
  if (threadIdx.x < 64) {
    const int h = threadIdx.x;
    const float inv = exp2f(-(float)h * (19.931568569324174f / 64.0f)); // 1e6^(-h/64)
    const float fr = (float)positions[t] * inv;
    csv[h] = cosf(fr);
    snv[h] = sinf(fr);
  }
  __syncthreads();
  // fold softmax scale * log2(e) into q so attention scores are exp2-ready
  const float SCQ = 0.08838834764831845f * 1.4426950408889634f;
  const float* row = qkv + (long)t * QKVC;
  for (int p = threadIdx.x; p < CN * 64; p += 256) {
    const int n = p >> 6, h = p & 63;
    const float x1 = row[n * CH + h], x2 = row[n * CH + h + 64];
    const float o1 = (x1 * csv[h] - x2 * snv[h]) * SCQ;
    const float o2 = (x2 * csv[h] + x1 * snv[h]) * SCQ;
    const long qi = ((long)(b * CN + n) * CS + s) * CH + h;
    qb[qi] = f2bf(o1);
    qb[qi + 64] = f2bf(o2);
  }
  for (int p = threadIdx.x; p < CK * 64; p += 256) {
    const int kk = p >> 6, h = p & 63;
    const float x1 = row[CN * CH + kk * CH + h], x2 = row[CN * CH + kk * CH + h + 64];
    const float o1 = x1 * csv[h] - x2 * snv[h];
    const float o2 = x2 * csv[h] + x1 * snv[h];
    const long ci = ((long)(b * CS + s) * CK + kk) * CH + h;
    cacheK[ci] = o1;
    cacheK[ci + 64] = o2;
    const long ki = ((long)(b * CK + kk) * CS + s) * CH + h;
    kb[ki] = f2bf(o1);
    kb[ki + 64] = f2bf(o2);
  }
}

// ---------------- V: cache f32 write + transposed bf16 [B][K][H][S] ----------------
__global__ __launch_bounds__(256) void v_transpose_kernel(const float* __restrict__ qkv,
                                                          float* __restrict__ cacheV,
                                                          u16* __restrict__ vt) {
  __shared__ float tile[32][33];
  const int s0 = blockIdx.x * 32, h0 = blockIdx.y * 32;
  const int bz = blockIdx.z;                 // b*K + kk
  const int b = bz >> 2, kk = bz & 3;
  const int tx = threadIdx.x, ty = threadIdx.y;
#pragma unroll
  for (int i = ty; i < 32; i += 8) {
    const int s = s0 + i;
    const float v = qkv[(long)(b * CS + s) * QKVC + CN * CH + CK * CH + kk * CH + h0 + tx];
    cacheV[((long)(b * CS + s) * CK + kk) * CH + h0 + tx] = v;
    tile[i][tx] = v;
  }
  __syncthreads();
#pragma unroll
  for (int i = ty; i < 32; i += 8)
    vt[((long)bz * CH + h0 + i) * CS + s0 + tx] = f2bf(tile[tx][i]);
}

// ---------------- flash attention: 4 waves x 32 q-rows, 64 kv/step (R9 dbuf version) ----------------
// Double-buffered K/V + counted vmcnt(8); head-major grid (XCD balance); K64-blocked output.
constexpr int PSTR = 72;
__global__ __launch_bounds__(256) void attn_kernel(const u16* __restrict__ qg,
                                                   const u16* __restrict__ kg,
                                                   const u16* __restrict__ vtg,
                                                   u16* __restrict__ og) {
  __shared__ u16 Ks[2][64 * 128];     // K tile [kv][h], 16B chunks XOR-swizzled by (row&7)
  __shared__ u16 Vt[2][128 * 64];     // V^T tile [h][kv], swizzled likewise
  __shared__ u16 Pl[4 * 32 * PSTR];   // per-wave P slab [q][kv0..63]

  const int bn = blockIdx.x;                 // b*N + n  (fast dim -> XCD round-robin)
  const int b = bn / CN, n = bn % CN;
  const int kvh = n / CG;
  const int q0 = ((int)gridDim.y - 1 - (int)blockIdx.y) * 128;  // long blocks first
  const int tid = threadIdx.x;
  const int wid = tid >> 6, lane = tid & 63;
  const int g = lane >> 4, r = lane & 15;
  const int wq0 = q0 + wid * 32;

  short8 qf[2][4];
#pragma unroll
  for (int qt = 0; qt < 2; ++qt) {
    const u16* qrp = qg + ((long)bn * CS + wq0 + qt * 16 + r) * CH;
#pragma unroll
    for (int c = 0; c < 4; ++c) qf[qt][c] = *(const short8*)(qrp + c * 32 + g * 8);
  }

  const u16* kbase = kg + (long)(b * CK + kvh) * CS * CH;   // [S][H]
  const u16* vbase = vtg + (long)(b * CK + kvh) * CH * CS;  // [H][S]

#define STAGE_KV(bufidx, jj) do { \
  _Pragma("unroll") for (int c = 0; c < 4; ++c) { \
    const int pbase = (wid * 4 + c) * 1024; \
    const int pp = pbase + lane * 16; \
    const int row = pp >> 8; \
    const int chl = ((pp >> 4) & 15) ^ (row & 7); \
    gload16(kbase + (long)((jj) + row) * CH + (chl << 3), &Ks[bufidx][pbase >> 1]); \
  } \
  _Pragma("unroll") for (int c = 0; c < 4; ++c) { \
    const int pbase = (wid * 4 + c) * 1024; \
    const int pp = pbase + lane * 16; \
    const int row = pp >> 7; \
    const int chl = ((pp >> 4) & 7) ^ (row & 7); \
    gload16(vbase + (long)row * CS + (jj) + (chl << 3), &Vt[bufidx][pbase >> 1]); \
  } \
} while (0)

  f32x4 oacc[2][8];
#pragma unroll
  for (int qt = 0; qt < 2; ++qt)
#pragma unroll
    for (int c = 0; c < 8; ++c) oacc[qt][c] = f32x4{0.f, 0.f, 0.f, 0.f};
  float m[2] = {-INFINITY, -INFINITY};
  float l[2] = {0.f, 0.f};

  const int nsteps = q0 / 64 + 2;
  STAGE_KV(0, 0);   // prologue: 8 loads in flight
  for (int it = 0; it < nsteps; ++it) {
    const int j0 = it * 64;
    const int cur = it & 1;
    if (it + 1 < nsteps) {
      STAGE_KV(cur ^ 1, j0 + 64);
      asm volatile("s_waitcnt vmcnt(8)" ::: "memory");
    } else {
      asm volatile("s_waitcnt vmcnt(0)" ::: "memory");
    }
    __builtin_amdgcn_s_barrier();

    if (j0 <= wq0 + 31) {
      f32x4 sc[2][4];
#pragma unroll
      for (int qt = 0; qt < 2; ++qt)
#pragma unroll
        for (int kt = 0; kt < 4; ++kt) sc[qt][kt] = f32x4{0.f, 0.f, 0.f, 0.f};
      __builtin_amdgcn_s_setprio(1);
#pragma unroll
      for (int kt = 0; kt < 4; ++kt) {
        short8 kf[4];
#pragma unroll
        for (int c = 0; c < 4; ++c)
          kf[c] = *(const short8*)&Ks[cur][(kt * 16 + r) * 128 + ((((c << 2) + g) ^ (r & 7)) << 3)];
#pragma unroll
        for (int qt = 0; qt < 2; ++qt)
#pragma unroll
          for (int c = 0; c < 4; ++c)
            sc[qt][kt] = __builtin_amdgcn_mfma_f32_16x16x32_bf16(kf[c], qf[qt][c], sc[qt][kt], 0, 0, 0);
      }
      __builtin_amdgcn_s_setprio(0);

      float pmax[2];
#pragma unroll
      for (int qt = 0; qt < 2; ++qt) {
        const int qq = wq0 + qt * 16 + r;
#pragma unroll
        for (int kt = 0; kt < 4; ++kt)
#pragma unroll
          for (int j = 0; j < 4; ++j) {
            const int kv = j0 + kt * 16 + g * 4 + j;
            if (kv > qq) sc[qt][kt][j] = -INFINITY;
          }
        float mx = sc[qt][0][0];
#pragma unroll
        for (int kt = 0; kt < 4; ++kt)
#pragma unroll
          for (int j = 0; j < 4; ++j) mx = fmaxf(mx, sc[qt][kt][j]);
        mx = fmaxf(mx, __shfl_xor(mx, 16));
        mx = fmaxf(mx, __shfl_xor(mx, 32));
        pmax[qt] = mx;
      }

      const bool ok = (pmax[0] <= m[0] + 8.f) && (pmax[1] <= m[1] + 8.f);
      if (!__all(ok)) {
#pragma unroll
        for (int qt = 0; qt < 2; ++qt) {
          const float mn = fmaxf(m[qt], pmax[qt]);
          const float fac = exp2f(m[qt] - mn);
          m[qt] = mn;
          l[qt] *= fac;
#pragma unroll
          for (int j = 0; j < 4; ++j) {
            const float fj = __shfl(fac, g * 4 + j);
#pragma unroll
            for (int c = 0; c < 8; ++c) oacc[qt][c][j] *= fj;
          }
        }
      }

#pragma unroll
      for (int qt = 0; qt < 2; ++qt) {
        float rsum = 0.f;
#pragma unroll
        for (int kt = 0; kt < 4; ++kt) {
          const float p0 = exp2f(sc[qt][kt][0] - m[qt]);
          const float p1 = exp2f(sc[qt][kt][1] - m[qt]);
          const float p2 = exp2f(sc[qt][kt][2] - m[qt]);
          const float p3 = exp2f(sc[qt][kt][3] - m[qt]);
          rsum += (p0 + p1) + (p2 + p3);
          uint2 pk;
          pk.x = (uint32_t)f2bf(p0) | ((uint32_t)f2bf(p1) << 16);
          pk.y = (uint32_t)f2bf(p2) | ((uint32_t)f2bf(p3) << 16);
          *(uint2*)&Pl[wid * 32 * PSTR + (qt * 16 + r) * PSTR + kt * 16 + g * 4] = pk;
        }
        rsum += __shfl_xor(rsum, 16);
        rsum += __shfl_xor(rsum, 32);
        l[qt] += rsum;
      }

      __builtin_amdgcn_s_setprio(1);
#pragma unroll
      for (int ks = 0; ks < 2; ++ks) {
        short8 pfq[2];
#pragma unroll
        for (int qt = 0; qt < 2; ++qt)
          pfq[qt] = *(const short8*)&Pl[wid * 32 * PSTR + (qt * 16 + r) * PSTR + ks * 32 + g * 8];
#pragma unroll
        for (int c = 0; c < 8; ++c) {
          const short8 vf = *(const short8*)&Vt[cur][(c * 16 + r) * 64 + ((((ks << 2) + g) ^ (r & 7)) << 3)];
#pragma unroll
          for (int qt = 0; qt < 2; ++qt)
            oacc[qt][c] = __builtin_amdgcn_mfma_f32_16x16x32_bf16(pfq[qt], vf, oacc[qt][c], 0, 0, 0);
        }
      }
      __builtin_amdgcn_s_setprio(0);
    }

    __builtin_amdgcn_s_barrier();   // protect buf cur from being re-staged next iter
  }
#undef STAGE_KV

  // ---- normalize + write bf16 K64-blocked: col = n*128 + c*16 + r ----
#pragma unroll
  for (int qt = 0; qt < 2; ++qt)
#pragma unroll
    for (int j = 0; j < 4; ++j) {
      const float linv = 1.0f / __shfl(l[qt], g * 4 + j);
      const long t = (long)b * CS + wq0 + qt * 16 + g * 4 + j;
#pragma unroll
      for (int c = 0; c < 8; ++c)
        og[((long)(n * 2 + (c >> 2)) * CT + t) * 64 + (c & 3) * 16 + r] = f2bf(oacc[qt][c][j] * linv);
    }
}

// ---------------- host ----------------
extern "C" void kernel_launch(void* const* d_in, const int* in_sizes, int n_in,
                              void* d_out, int out_size, void* d_ws, size_t ws_size,
                              hipStream_t stream) {
  (void)in_sizes; (void)n_in; (void)out_size; (void)ws_size;
  const float* x  = (const float*)d_in[1];
  const int* positions = (const int*)d_in[2];
  const float* Wq = (const float*)d_in[3];
  const float* bq = (const float*)d_in[4];
  const float* Wk = (const float*)d_in[5];
  const float* bk = (const float*)d_in[6];
  const float* Wv = (const float*)d_in[7];
  const float* bv = (const float*)d_in[8];
  const float* Wo = (const float*)d_in[9];
  float* out = (float*)d_out;

  char* ws = (char*)d_ws;
  u16*   xb     = (u16*)(ws + 0L);            // 29,360,128 B  x bf16 K32-blocked [112][T][32]
  u16*   w1t    = (u16*)(ws + 29360128L);     // 33,030,144 B  W_qkv^T bf16 K32-blocked [112][4608][32]
  u16*   wot    = (u16*)(ws + 62390272L);     // 25,690,112 B  Wo^T bf16 K64-blocked [56][3584][64]
  float* qkv    = (float*)(ws + 88080384L);   // 75,497,472 B  qkv f32 [T][4608]
  u16*   attn_b = (u16*)qkv;                  // aliased: attn out bf16 K64-blocked [56][T][64]
  u16*   qb     = (u16*)(ws + 163577856L);    // 29,360,128 B  q roped bf16 [B][N][S][H]
  u16*   kb2    = (u16*)(ws + 192937984L);    //  4,194,304 B  k roped bf16 [B][K][S][H]
  u16*   vt     = (u16*)(ws + 197132288L);    //  4,194,304 B  V^T bf16 [B][K][H][S]
  // total 201,326,592 B

  cvt_blk_kernel<<<dim3((CT * (long)CD) / 1024), 256, 0, stream>>>(x, xb, (long)CT * CD);
  transpose_cvt_kernel<5><<<dim3(112, 112), dim3(32, 8), 0, stream>>>(Wq, w1t, CN * CH, 0, QKVC);
  transpose_cvt_kernel<5><<<dim3(16, 112), dim3(32, 8), 0, stream>>>(Wk, w1t, CK * CH, CN * CH, QKVC);
  transpose_cvt_kernel<5><<<dim3(16, 112), dim3(32, 8), 0, stream>>>(Wv, w1t, CK * CH, CN * CH + CK * CH, QKVC);
  transpose_cvt_kernel<6><<<dim3(112, 112), dim3(32, 8), 0, stream>>>(Wo, wot, CD, 0, CD);

  // QKV projection: 8 XCD x 2 bm x 36 bn = 576 blocks of 256x128, BK=32
  gemm256_kernel<1><<<dim3(16 * (QKVC / 128)), 512, 0, stream>>>(xb, w1t, qkv, bq, bk, bv, QKVC, CD);

  rope_scatter_kernel<<<dim3(CT), 256, 0, stream>>>(qkv, positions, qb, kb2, out);
  v_transpose_kernel<<<dim3(CS / 32, CH / 32, CB * CK), dim3(32, 8), 0, stream>>>(qkv, out + KV_HALF, vt);

  attn_kernel<<<dim3(CB * CN, CS / 128), 256, 0, stream>>>(qb, kb2, vt, attn_b);

  // O projection: 8 XCD x 2 bm x 14 bn = 224 blocks of 256x256, 4-phase fine interleave
  gemm_8ph_kernel<<<dim3(16 * (CD / 256)), 512, 0, stream>>>(attn_b, wot, out + 2 * KV_HALF, CD, CD);
}

// Round 17
// 444.085 us; speedup vs baseline: 1.0352x; 1.0352x over previous
//
#include <hip/hip_runtime.h>
#include <stdint.h>

typedef unsigned short u16;
typedef __attribute__((ext_vector_type(8))) short short8;
typedef __attribute__((ext_vector_type(4))) float f32x4;
typedef __attribute__((ext_vector_type(4))) unsigned short u16x4;

constexpr int CB = 4, CS = 1024, CD = 3584, CN = 28, CK = 4, CH = 128, CG = 7;
constexpr int CT = CB * CS;                    // 4096 tokens
constexpr int QKVC = CN * CH + 2 * CK * CH;    // 4608 fused qkv cols
constexpr long KV_HALF = (long)CB * CS * CK * CH; // 2,097,152 floats per cache half

__device__ __forceinline__ u16 f2bf(float f) {
  union { float f; uint32_t u; } c; c.f = f;
  uint32_t u = c.u + 0x7fffu + ((c.u >> 16) & 1);   // RNE to bf16
  return (u16)(u >> 16);
}

// async global->LDS, 16B per lane; LDS dest must be wave-uniform base (+lane*16 implicit)
__device__ __forceinline__ void gload16(const void* g, void* l) {
  __builtin_amdgcn_global_load_lds(
      (const __attribute__((address_space(1))) unsigned int*)(uintptr_t)g,
      (__attribute__((address_space(3))) unsigned int*)(uint32_t)(uintptr_t)l,
      16, 0, 0);
}

// ---------------- f32 [T][D] -> bf16 K-blocked [D/32][T][32] ----------------
__global__ __launch_bounds__(256) void cvt_blk_kernel(const float* __restrict__ in,
                                                      u16* __restrict__ outp, long n) {
  long i = ((long)blockIdx.x * 256 + threadIdx.x) * 4;
  if (i < n) {
    const float4 v = *(const float4*)(in + i);
    const int t = (int)(i / CD), d = (int)(i % CD);
    u16x4 o; o.x = f2bf(v.x); o.y = f2bf(v.y); o.z = f2bf(v.z); o.w = f2bf(v.w);
    *(u16x4*)(outp + ((long)(d >> 5) * CT + t) * 32 + (d & 31)) = o;
  }
}

// ---- transpose f32 src[.][C] -> bf16 K-blocked dst[K/32][RT][32], K = src row dim ----
__global__ __launch_bounds__(256) void transpose_cvt_kernel(const float* __restrict__ src,
                                                            u16* __restrict__ dst,
                                                            int C, int dstOff, int RT) {
  __shared__ float tile[32][33];
  const int c0 = blockIdx.x * 32, r0 = blockIdx.y * 32;
  const int tx = threadIdx.x, ty = threadIdx.y;
#pragma unroll
  for (int i = ty; i < 32; i += 8)
    tile[i][tx] = src[(long)(r0 + i) * C + c0 + tx];
  __syncthreads();
#pragma unroll
  for (int i = ty; i < 32; i += 8)
    dst[((long)(r0 >> 5) * RT + dstOff + c0 + i) * 32 + tx] = f2bf(tile[tx][i]);
}

// ---------------- 256x128 bf16 GEMM on K-blocked operands, BK=32 triple-buffered ----------------
// (round-9 proven state: launch_bounds(512,4) -> VGPR 56, no spill; 0 conflicts;
//  2-tile lookahead vmcnt(6); XCD-cooperative mapping; contiguous 16KB/8KB tile streams)
__device__ __forceinline__ void stage_A(u16* dst, const u16* srcTile, int w, int lane) {
  const int ci0 = (w << 7) + lane;        // 1024 chunks of 16B; 2 per thread
  const int ci1 = ci0 + 64;
  const int l0 = (ci0 & 3) ^ ((ci0 >> 3) & 3);
  const int l1 = (ci1 & 3) ^ ((ci1 >> 3) & 3);
  gload16(srcTile + ((ci0 >> 2) << 5) + (l0 << 3), dst + (w << 10));
  gload16(srcTile + ((ci1 >> 2) << 5) + (l1 << 3), dst + (w << 10) + 512);
}
__device__ __forceinline__ void stage_B(u16* dst, const u16* srcTile, int w, int lane) {
  const int ci = (w << 6) + lane;         // 512 chunks; 1 per thread
  const int l = (ci & 3) ^ ((ci >> 3) & 3);
  gload16(srcTile + ((ci >> 2) << 5) + (l << 3), dst + (w << 9));
}

template <int ADD_BIAS>
__global__ __launch_bounds__(512, 4) void gemm256_kernel(const u16* __restrict__ Ablk,
                                                         const u16* __restrict__ Bblk,
                                                         float* __restrict__ C,
                                                         const float* __restrict__ bq,
                                                         const float* __restrict__ bk2,
                                                         const float* __restrict__ bv,
                                                         int Ncol, int Kd) {
  __shared__ u16 Al[3][8192];   // 3 x 16KB
  __shared__ u16 Bl[3][4096];   // 3 x 8KB
  const int tid = threadIdx.x;
  const int w = tid >> 6, lane = tid & 63;
  const int g = lane >> 4, r = lane & 15;
  const int gs = (g ^ ((r >> 1) & 3)) << 3;   // swizzled fragment column (u16 units)
  // XCD-cooperative mapping
  const int xcd = (int)blockIdx.x & 7, c = (int)blockIdx.x >> 3;
  const int bm = ((xcd << 1) + (c & 1)) << 8;
  const int bn = (c >> 1) << 7;
  const int wM = (w >> 1) * 64;   // 4 M-slots
  const int wN = (w & 1) * 64;    // 2 N-slots

  f32x4 acc[4][4];
#pragma unroll
  for (int mi = 0; mi < 4; ++mi)
#pragma unroll
    for (int ni = 0; ni < 4; ++ni) acc[mi][ni] = f32x4{0.f, 0.f, 0.f, 0.f};

#define ATILE(t) (Ablk + ((long)(t) * CT + bm) * 32)
#define BTILE(t) (Bblk + ((long)(t) * Ncol + bn) * 32)
  stage_A(&Al[0][0], ATILE(0), w, lane);
  stage_B(&Bl[0][0], BTILE(0), w, lane);
  stage_A(&Al[1][0], ATILE(1), w, lane);
  stage_B(&Bl[1][0], BTILE(1), w, lane);

  const int NT = Kd >> 5;
  for (int t = 0; t < NT; ++t) {
    const int p = t % 3;
    if (t + 2 < NT) {
      const int f = (t + 2) % 3;
      stage_A(&Al[f][0], ATILE(t + 2), w, lane);
      stage_B(&Bl[f][0], BTILE(t + 2), w, lane);
      asm volatile("s_waitcnt vmcnt(6)" ::: "memory");   // tile t landed; t+1,t+2 in flight
    } else if (t + 1 < NT) {
      asm volatile("s_waitcnt vmcnt(3)" ::: "memory");
    } else {
      asm volatile("s_waitcnt vmcnt(0)" ::: "memory");
    }
    __builtin_amdgcn_s_barrier();
    short8 af[4], bf[4];
#pragma unroll
    for (int mi = 0; mi < 4; ++mi)
      af[mi] = *(const short8*)&Al[p][(wM + mi * 16 + r) * 32 + gs];
#pragma unroll
    for (int ni = 0; ni < 4; ++ni)
      bf[ni] = *(const short8*)&Bl[p][(wN + ni * 16 + r) * 32 + gs];
    __builtin_amdgcn_s_setprio(1);
#pragma unroll
    for (int mi = 0; mi < 4; ++mi)
#pragma unroll
      for (int ni = 0; ni < 4; ++ni)
        acc[mi][ni] = __builtin_amdgcn_mfma_f32_16x16x32_bf16(af[mi], bf[ni], acc[mi][ni], 0, 0, 0);
    __builtin_amdgcn_s_setprio(0);
    asm volatile("s_waitcnt lgkmcnt(0)" ::: "memory");   // reads of buf p retired
    __builtin_amdgcn_s_barrier();                        // before buf p is re-staged
  }
#undef ATILE
#undef BTILE

#pragma unroll
  for (int mi = 0; mi < 4; ++mi) {
#pragma unroll
    for (int ni = 0; ni < 4; ++ni) {
      const int col = bn + wN + ni * 16 + r;
      float badd = 0.f;
      if (ADD_BIAS)
        badd = (col < CN * CH) ? bq[col]
             : (col < CN * CH + CK * CH) ? bk2[col - CN * CH]
                                         : bv[col - CN * CH - CK * CH];
#pragma unroll
      for (int j = 0; j < 4; ++j) {
        const int row = bm + wM + mi * 16 + g * 4 + j;
        C[(long)row * Ncol + col] = acc[mi][ni][j] + badd;
      }
    }
  }
}

// ---------------- RoPE + scatter: q->bf16 (pre-scaled) [B][N][S][H], k->cache f32 + bf16 [B][K][S][H] ----------------
__global__ __launch_bounds__(256) void rope_scatter_kernel(const float* __restrict__ qkv,
                                                           const int* __restrict__ positions,
                                                           u16* __restrict__ qb,
                                                           u16* __restrict__ kb,
                                                           float* __restrict__ cacheK) {
  const int t = blockIdx.x;
  const int b = t / CS, s = t % CS;
  __shared__ float csv[64], snv[64];
  if (threadIdx.x < 64) {
    const int h = threadIdx.x;
    const float inv = exp2f(-(float)h * (19.931568569324174f / 64.0f)); // 1e6^(-h/64)
    const float fr = (float)positions[t] * inv;
    csv[h] = cosf(fr);
    snv[h] = sinf(fr);
  }
  __syncthreads();
  // fold softmax scale * log2(e) into q so attention scores are exp2-ready
  const float SCQ = 0.08838834764831845f * 1.4426950408889634f;
  const float* row = qkv + (long)t * QKVC;
  for (int p = threadIdx.x; p < CN * 64; p += 256) {
    const int n = p >> 6, h = p & 63;
    const float x1 = row[n * CH + h], x2 = row[n * CH + h + 64];
    const float o1 = (x1 * csv[h] - x2 * snv[h]) * SCQ;
    const float o2 = (x2 * csv[h] + x1 * snv[h]) * SCQ;
    const long qi = ((long)(b * CN + n) * CS + s) * CH + h;
    qb[qi] = f2bf(o1);
    qb[qi + 64] = f2bf(o2);
  }
  for (int p = threadIdx.x; p < CK * 64; p += 256) {
    const int kk = p >> 6, h = p & 63;
    const float x1 = row[CN * CH + kk * CH + h], x2 = row[CN * CH + kk * CH + h + 64];
    const float o1 = x1 * csv[h] - x2 * snv[h];
    const float o2 = x2 * csv[h] + x1 * snv[h];
    const long ci = ((long)(b * CS + s) * CK + kk) * CH + h;
    cacheK[ci] = o1;
    cacheK[ci + 64] = o2;
    const long ki = ((long)(b * CK + kk) * CS + s) * CH + h;
    kb[ki] = f2bf(o1);
    kb[ki + 64] = f2bf(o2);
  }
}

// ---------------- V: cache f32 write + transposed bf16 [B][K][H][S] ----------------
__global__ __launch_bounds__(256) void v_transpose_kernel(const float* __restrict__ qkv,
                                                          float* __restrict__ cacheV,
                                                          u16* __restrict__ vt) {
  __shared__ float tile[32][33];
  const int s0 = blockIdx.x * 32, h0 = blockIdx.y * 32;
  const int bz = blockIdx.z;                 // b*K + kk
  const int b = bz >> 2, kk = bz & 3;
  const int tx = threadIdx.x, ty = threadIdx.y;
#pragma unroll
  for (int i = ty; i < 32; i += 8) {
    const int s = s0 + i;
    const float v = qkv[(long)(b * CS + s) * QKVC + CN * CH + CK * CH + kk * CH + h0 + tx];
    cacheV[((long)(b * CS + s) * CK + kk) * CH + h0 + tx] = v;
    tile[i][tx] = v;
  }
  __syncthreads();
#pragma unroll
  for (int i = ty; i < 32; i += 8)
    vt[((long)bz * CH + h0 + i) * CS + s0 + tx] = f2bf(tile[tx][i]);
}

// ---------------- flash attention: 4 waves x 32 q-rows, 64 kv/step (R9 dbuf version) ----------------
// Double-buffered K/V + counted vmcnt(8); head-major grid (XCD balance); blocked output.
constexpr int PSTR = 72;
__global__ __launch_bounds__(256) void attn_kernel(const u16* __restrict__ qg,
                                                   const u16* __restrict__ kg,
                                                   const u16* __restrict__ vtg,
                                                   u16* __restrict__ og) {
  __shared__ u16 Ks[2][64 * 128];     // K tile [kv][h], 16B chunks XOR-swizzled by (row&7)
  __shared__ u16 Vt[2][128 * 64];     // V^T tile [h][kv], swizzled likewise
  __shared__ u16 Pl[4 * 32 * PSTR];   // per-wave P slab [q][kv0..63]

  const int bn = blockIdx.x;                 // b*N + n  (fast dim -> XCD round-robin)
  const int b = bn / CN, n = bn % CN;
  const int kvh = n / CG;
  const int q0 = ((int)gridDim.y - 1 - (int)blockIdx.y) * 128;  // long blocks first
  const int tid = threadIdx.x;
  const int wid = tid >> 6, lane = tid & 63;
  const int g = lane >> 4, r = lane & 15;
  const int wq0 = q0 + wid * 32;

  short8 qf[2][4];
#pragma unroll
  for (int qt = 0; qt < 2; ++qt) {
    const u16* qrp = qg + ((long)bn * CS + wq0 + qt * 16 + r) * CH;
#pragma unroll
    for (int c = 0; c < 4; ++c) qf[qt][c] = *(const short8*)(qrp + c * 32 + g * 8);
  }

  const u16* kbase = kg + (long)(b * CK + kvh) * CS * CH;   // [S][H]
  const u16* vbase = vtg + (long)(b * CK + kvh) * CH * CS;  // [H][S]

#define STAGE_KV(bufidx, jj) do { \
  _Pragma("unroll") for (int c = 0; c < 4; ++c) { \
    const int pbase = (wid * 4 + c) * 1024; \
    const int pp = pbase + lane * 16; \
    const int row = pp >> 8; \
    const int chl = ((pp >> 4) & 15) ^ (row & 7); \
    gload16(kbase + (long)((jj) + row) * CH + (chl << 3), &Ks[bufidx][pbase >> 1]); \
  } \
  _Pragma("unroll") for (int c = 0; c < 4; ++c) { \
    const int pbase = (wid * 4 + c) * 1024; \
    const int pp = pbase + lane * 16; \
    const int row = pp >> 7; \
    const int chl = ((pp >> 4) & 7) ^ (row & 7); \
    gload16(vbase + (long)row * CS + (jj) + (chl << 3), &Vt[bufidx][pbase >> 1]); \
  } \
} while (0)

  f32x4 oacc[2][8];
#pragma unroll
  for (int qt = 0; qt < 2; ++qt)
#pragma unroll
    for (int c = 0; c < 8; ++c) oacc[qt][c] = f32x4{0.f, 0.f, 0.f, 0.f};
  float m[2] = {-INFINITY, -INFINITY};
  float l[2] = {0.f, 0.f};

  const int nsteps = q0 / 64 + 2;
  STAGE_KV(0, 0);   // prologue: 8 loads in flight
  for (int it = 0; it < nsteps; ++it) {
    const int j0 = it * 64;
    const int cur = it & 1;
    if (it + 1 < nsteps) {
      STAGE_KV(cur ^ 1, j0 + 64);
      asm volatile("s_waitcnt vmcnt(8)" ::: "memory");
    } else {
      asm volatile("s_waitcnt vmcnt(0)" ::: "memory");
    }
    __builtin_amdgcn_s_barrier();

    if (j0 <= wq0 + 31) {
      f32x4 sc[2][4];
#pragma unroll
      for (int qt = 0; qt < 2; ++qt)
#pragma unroll
        for (int kt = 0; kt < 4; ++kt) sc[qt][kt] = f32x4{0.f, 0.f, 0.f, 0.f};
      __builtin_amdgcn_s_setprio(1);
#pragma unroll
      for (int kt = 0; kt < 4; ++kt) {
        short8 kf[4];
#pragma unroll
        for (int c = 0; c < 4; ++c)
          kf[c] = *(const short8*)&Ks[cur][(kt * 16 + r) * 128 + ((((c << 2) + g) ^ (r & 7)) << 3)];
#pragma unroll
        for (int qt = 0; qt < 2; ++qt)
#pragma unroll
          for (int c = 0; c < 4; ++c)
            sc[qt][kt] = __builtin_amdgcn_mfma_f32_16x16x32_bf16(kf[c], qf[qt][c], sc[qt][kt], 0, 0, 0);
      }
      __builtin_amdgcn_s_setprio(0);

      float pmax[2];
#pragma unroll
      for (int qt = 0; qt < 2; ++qt) {
        const int qq = wq0 + qt * 16 + r;
#pragma unroll
        for (int kt = 0; kt < 4; ++kt)
#pragma unroll
          for (int j = 0; j < 4; ++j) {
            const int kv = j0 + kt * 16 + g * 4 + j;
            if (kv > qq) sc[qt][kt][j] = -INFINITY;
          }
        float mx = sc[qt][0][0];
#pragma unroll
        for (int kt = 0; kt < 4; ++kt)
#pragma unroll
          for (int j = 0; j < 4; ++j) mx = fmaxf(mx, sc[qt][kt][j]);
        mx = fmaxf(mx, __shfl_xor(mx, 16));
        mx = fmaxf(mx, __shfl_xor(mx, 32));
        pmax[qt] = mx;
      }

      const bool ok = (pmax[0] <= m[0] + 8.f) && (pmax[1] <= m[1] + 8.f);
      if (!__all(ok)) {
#pragma unroll
        for (int qt = 0; qt < 2; ++qt) {
          const float mn = fmaxf(m[qt], pmax[qt]);
          const float fac = exp2f(m[qt] - mn);
          m[qt] = mn;
          l[qt] *= fac;
#pragma unroll
          for (int j = 0; j < 4; ++j) {
            const float fj = __shfl(fac, g * 4 + j);
#pragma unroll
            for (int c = 0; c < 8; ++c) oacc[qt][c][j] *= fj;
          }
        }
      }

#pragma unroll
      for (int qt = 0; qt < 2; ++qt) {
        float rsum = 0.f;
#pragma unroll
        for (int kt = 0; kt < 4; ++kt) {
          const float p0 = exp2f(sc[qt][kt][0] - m[qt]);
          const float p1 = exp2f(sc[qt][kt][1] - m[qt]);
          const float p2 = exp2f(sc[qt][kt][2] - m[qt]);
          const float p3 = exp2f(sc[qt][kt][3] - m[qt]);
          rsum += (p0 + p1) + (p2 + p3);
          uint2 pk;
          pk.x = (uint32_t)f2bf(p0) | ((uint32_t)f2bf(p1) << 16);
          pk.y = (uint32_t)f2bf(p2) | ((uint32_t)f2bf(p3) << 16);
          *(uint2*)&Pl[wid * 32 * PSTR + (qt * 16 + r) * PSTR + kt * 16 + g * 4] = pk;
        }
        rsum += __shfl_xor(rsum, 16);
        rsum += __shfl_xor(rsum, 32);
        l[qt] += rsum;
      }

      __builtin_amdgcn_s_setprio(1);
#pragma unroll
      for (int ks = 0; ks < 2; ++ks) {
        short8 pfq[2];
#pragma unroll
        for (int qt = 0; qt < 2; ++qt)
          pfq[qt] = *(const short8*)&Pl[wid * 32 * PSTR + (qt * 16 + r) * PSTR + ks * 32 + g * 8];
#pragma unroll
        for (int c = 0; c < 8; ++c) {
          const short8 vf = *(const short8*)&Vt[cur][(c * 16 + r) * 64 + ((((ks << 2) + g) ^ (r & 7)) << 3)];
#pragma unroll
          for (int qt = 0; qt < 2; ++qt)
            oacc[qt][c] = __builtin_amdgcn_mfma_f32_16x16x32_bf16(pfq[qt], vf, oacc[qt][c], 0, 0, 0);
        }
      }
      __builtin_amdgcn_s_setprio(0);
    }

    __builtin_amdgcn_s_barrier();   // protect buf cur from being re-staged next iter
  }
#undef STAGE_KV

  // ---- normalize + write bf16 K-blocked: col = n*128 + c*16 + r ----
#pragma unroll
  for (int qt = 0; qt < 2; ++qt)
#pragma unroll
    for (int j = 0; j < 4; ++j) {
      const float linv = 1.0f / __shfl(l[qt], g * 4 + j);
      const long t = (long)b * CS + wq0 + qt * 16 + g * 4 + j;
#pragma unroll
      for (int c = 0; c < 8; ++c)
        og[((long)(n * 4 + (c >> 1)) * CT + t) * 32 + (c & 1) * 16 + r] = f2bf(oacc[qt][c][j] * linv);
    }
}

// ---------------- host ----------------
extern "C" void kernel_launch(void* const* d_in, const int* in_sizes, int n_in,
                              void* d_out, int out_size, void* d_ws, size_t ws_size,
                              hipStream_t stream) {
  (void)in_sizes; (void)n_in; (void)out_size; (void)ws_size;
  const float* x  = (const float*)d_in[1];
  const int* positions = (const int*)d_in[2];
  const float* Wq = (const float*)d_in[3];
  const float* bq = (const float*)d_in[4];
  const float* Wk = (const float*)d_in[5];
  const float* bk = (const float*)d_in[6];
  const float* Wv = (const float*)d_in[7];
  const float* bv = (const float*)d_in[8];
  const float* Wo = (const float*)d_in[9];
  float* out = (float*)d_out;

  char* ws = (char*)d_ws;
  u16*   xb     = (u16*)(ws + 0L);            // 29,360,128 B  x bf16 blocked [112][T][32]
  u16*   w1t    = (u16*)(ws + 29360128L);     // 33,030,144 B  W_qkv^T bf16 blocked [112][4608][32]
  u16*   wot    = (u16*)(ws + 62390272L);     // 25,690,112 B  Wo^T bf16 blocked [112][3584][32]
  float* qkv    = (float*)(ws + 88080384L);   // 75,497,472 B  qkv f32 [T][4608]
  u16*   attn_b = (u16*)qkv;                  // aliased: attn out bf16 blocked [112][T][32]
  u16*   qb     = (u16*)(ws + 163577856L);    // 29,360,128 B  q roped bf16 [B][N][S][H]
  u16*   kb2    = (u16*)(ws + 192937984L);    //  4,194,304 B  k roped bf16 [B][K][S][H]
  u16*   vt     = (u16*)(ws + 197132288L);    //  4,194,304 B  V^T bf16 [B][K][H][S]
  // total 201,326,592 B

  cvt_blk_kernel<<<dim3((CT * (long)CD) / 1024), 256, 0, stream>>>(x, xb, (long)CT * CD);
  transpose_cvt_kernel<<<dim3(112, 112), dim3(32, 8), 0, stream>>>(Wq, w1t, CN * CH, 0, QKVC);
  transpose_cvt_kernel<<<dim3(16, 112), dim3(32, 8), 0, stream>>>(Wk, w1t, CK * CH, CN * CH, QKVC);
  transpose_cvt_kernel<<<dim3(16, 112), dim3(32, 8), 0, stream>>>(Wv, w1t, CK * CH, CN * CH + CK * CH, QKVC);
  transpose_cvt_kernel<<<dim3(112, 112), dim3(32, 8), 0, stream>>>(Wo, wot, CD, 0, CD);

  // QKV projection: 8 XCD x 2 bm x 36 bn = 576 blocks of 256x128
  gemm256_kernel<1><<<dim3(16 * (QKVC / 128)), 512, 0, stream>>>(xb, w1t, qkv, bq, bk, bv, QKVC, CD);

  rope_scatter_kernel<<<dim3(CT), 256, 0, stream>>>(qkv, positions, qb, kb2, out);
  v_transpose_kernel<<<dim3(CS / 32, CH / 32, CB * CK), dim3(32, 8), 0, stream>>>(qkv, out + KV_HALF, vt);

  attn_kernel<<<dim3(CB * CN, CS / 128), 256, 0, stream>>>(qb, kb2, vt, attn_b);

  // O projection: 8 XCD x 2 bm x 28 bn = 448 blocks of 256x128
  gemm256_kernel<0><<<dim3(16 * (CD / 128)), 512, 0, stream>>>(attn_b, wot, out + 2 * KV_HALF,
                                                               nullptr, nullptr, nullptr, CD, CD);
}

// Round 18
// 440.685 us; speedup vs baseline: 1.0432x; 1.0077x over previous
//
#include <hip/hip_runtime.h>
#include <stdint.h>

typedef unsigned short u16;
typedef __attribute__((ext_vector_type(8))) short short8;
typedef __attribute__((ext_vector_type(4))) float f32x4;
typedef __attribute__((ext_vector_type(4))) unsigned short u16x4;

constexpr int CB = 4, CS = 1024, CD = 3584, CN = 28, CK = 4, CH = 128, CG = 7;
constexpr int CT = CB * CS;                    // 4096 tokens
constexpr int QKVC = CN * CH + 2 * CK * CH;    // 4608 fused qkv cols
constexpr long KV_HALF = (long)CB * CS * CK * CH; // 2,097,152 floats per cache half

__device__ __forceinline__ u16 f2bf(float f) {
  union { float f; uint32_t u; } c; c.f = f;
  uint32_t u = c.u + 0x7fffu + ((c.u >> 16) & 1);   // RNE to bf16
  return (u16)(u >> 16);
}
__device__ __forceinline__ float bf2f(u16 v) {
  union { uint32_t u; float f; } c; c.u = (uint32_t)v << 16;
  return c.f;
}

// async global->LDS, 16B per lane; LDS dest must be wave-uniform base (+lane*16 implicit)
__device__ __forceinline__ void gload16(const void* g, void* l) {
  __builtin_amdgcn_global_load_lds(
      (const __attribute__((address_space(1))) unsigned int*)(uintptr_t)g,
      (__attribute__((address_space(3))) unsigned int*)(uint32_t)(uintptr_t)l,
      16, 0, 0);
}

// ---------------- f32 [T][D] -> bf16 K-blocked [D/32][T][32] ----------------
__global__ __launch_bounds__(256) void cvt_blk_kernel(const float* __restrict__ in,
                                                      u16* __restrict__ outp, long n) {
  long i = ((long)blockIdx.x * 256 + threadIdx.x) * 4;
  if (i < n) {
    const float4 v = *(const float4*)(in + i);
    const int t = (int)(i / CD), d = (int)(i % CD);
    u16x4 o; o.x = f2bf(v.x); o.y = f2bf(v.y); o.z = f2bf(v.z); o.w = f2bf(v.w);
    *(u16x4*)(outp + ((long)(d >> 5) * CT + t) * 32 + (d & 31)) = o;
  }
}

// ---- transpose f32 src[.][C] -> bf16 K-blocked dst[K/32][RT][32], K = src row dim ----
__global__ __launch_bounds__(256) void transpose_cvt_kernel(const float* __restrict__ src,
                                                            u16* __restrict__ dst,
                                                            int C, int dstOff, int RT) {
  __shared__ float tile[32][33];
  const int c0 = blockIdx.x * 32, r0 = blockIdx.y * 32;
  const int tx = threadIdx.x, ty = threadIdx.y;
#pragma unroll
  for (int i = ty; i < 32; i += 8)
    tile[i][tx] = src[(long)(r0 + i) * C + c0 + tx];
  __syncthreads();
#pragma unroll
  for (int i = ty; i < 32; i += 8)
    dst[((long)(r0 >> 5) * RT + dstOff + c0 + i) * 32 + tx] = f2bf(tile[tx][i]);
}

// ---------------- 256x128 bf16 GEMM on K-blocked operands, BK=32 triple-buffered ----------------
// (round-9 proven schedule: launch_bounds(512,4) -> VGPR 56, no spill; 0 conflicts;
//  2-tile lookahead vmcnt(6); XCD-cooperative mapping; contiguous 16KB/8KB tile streams)
// ADD_BIAS=1 path writes bf16 output (u16), ADD_BIAS=0 path writes f32.
__device__ __forceinline__ void stage_A(u16* dst, const u16* srcTile, int w, int lane) {
  const int ci0 = (w << 7) + lane;        // 1024 chunks of 16B; 2 per thread
  const int ci1 = ci0 + 64;
  const int l0 = (ci0 & 3) ^ ((ci0 >> 3) & 3);
  const int l1 = (ci1 & 3) ^ ((ci1 >> 3) & 3);
  gload16(srcTile + ((ci0 >> 2) << 5) + (l0 << 3), dst + (w << 10));
  gload16(srcTile + ((ci1 >> 2) << 5) + (l1 << 3), dst + (w << 10) + 512);
}
__device__ __forceinline__ void stage_B(u16* dst, const u16* srcTile, int w, int lane) {
  const int ci = (w << 6) + lane;         // 512 chunks; 1 per thread
  const int l = (ci & 3) ^ ((ci >> 3) & 3);
  gload16(srcTile + ((ci >> 2) << 5) + (l << 3), dst + (w << 9));
}

template <int ADD_BIAS>
__global__ __launch_bounds__(512, 4) void gemm256_kernel(const u16* __restrict__ Ablk,
                                                         const u16* __restrict__ Bblk,
                                                         void* __restrict__ Cout,
                                                         const float* __restrict__ bq,
                                                         const float* __restrict__ bk2,
                                                         const float* __restrict__ bv,
                                                         int Ncol, int Kd) {
  __shared__ u16 Al[3][8192];   // 3 x 16KB
  __shared__ u16 Bl[3][4096];   // 3 x 8KB
  const int tid = threadIdx.x;
  const int w = tid >> 6, lane = tid & 63;
  const int g = lane >> 4, r = lane & 15;
  const int gs = (g ^ ((r >> 1) & 3)) << 3;   // swizzled fragment column (u16 units)
  // XCD-cooperative mapping
  const int xcd = (int)blockIdx.x & 7, c = (int)blockIdx.x >> 3;
  const int bm = ((xcd << 1) + (c & 1)) << 8;
  const int bn = (c >> 1) << 7;
  const int wM = (w >> 1) * 64;   // 4 M-slots
  const int wN = (w & 1) * 64;    // 2 N-slots

  f32x4 acc[4][4];
#pragma unroll
  for (int mi = 0; mi < 4; ++mi)
#pragma unroll
    for (int ni = 0; ni < 4; ++ni) acc[mi][ni] = f32x4{0.f, 0.f, 0.f, 0.f};

#define ATILE(t) (Ablk + ((long)(t) * CT + bm) * 32)
#define BTILE(t) (Bblk + ((long)(t) * Ncol + bn) * 32)
  stage_A(&Al[0][0], ATILE(0), w, lane);
  stage_B(&Bl[0][0], BTILE(0), w, lane);
  stage_A(&Al[1][0], ATILE(1), w, lane);
  stage_B(&Bl[1][0], BTILE(1), w, lane);

  const int NT = Kd >> 5;
  for (int t = 0; t < NT; ++t) {
    const int p = t % 3;
    if (t + 2 < NT) {
      const int f = (t + 2) % 3;
      stage_A(&Al[f][0], ATILE(t + 2), w, lane);
      stage_B(&Bl[f][0], BTILE(t + 2), w, lane);
      asm volatile("s_waitcnt vmcnt(6)" ::: "memory");   // tile t landed; t+1,t+2 in flight
    } else if (t + 1 < NT) {
      asm volatile("s_waitcnt vmcnt(3)" ::: "memory");
    } else {
      asm volatile("s_waitcnt vmcnt(0)" ::: "memory");
    }
    __builtin_amdgcn_s_barrier();
    short8 af[4], bf[4];
#pragma unroll
    for (int mi = 0; mi < 4; ++mi)
      af[mi] = *(const short8*)&Al[p][(wM + mi * 16 + r) * 32 + gs];
#pragma unroll
    for (int ni = 0; ni < 4; ++ni)
      bf[ni] = *(const short8*)&Bl[p][(wN + ni * 16 + r) * 32 + gs];
    __builtin_amdgcn_s_setprio(1);
#pragma unroll
    for (int mi = 0; mi < 4; ++mi)
#pragma unroll
      for (int ni = 0; ni < 4; ++ni)
        acc[mi][ni] = __builtin_amdgcn_mfma_f32_16x16x32_bf16(af[mi], bf[ni], acc[mi][ni], 0, 0, 0);
    __builtin_amdgcn_s_setprio(0);
    asm volatile("s_waitcnt lgkmcnt(0)" ::: "memory");   // reads of buf p retired
    __builtin_amdgcn_s_barrier();                        // before buf p is re-staged
  }
#undef ATILE
#undef BTILE

#pragma unroll
  for (int mi = 0; mi < 4; ++mi) {
#pragma unroll
    for (int ni = 0; ni < 4; ++ni) {
      const int col = bn + wN + ni * 16 + r;
      float badd = 0.f;
      if (ADD_BIAS)
        badd = (col < CN * CH) ? bq[col]
             : (col < CN * CH + CK * CH) ? bk2[col - CN * CH]
                                         : bv[col - CN * CH - CK * CH];
#pragma unroll
      for (int j = 0; j < 4; ++j) {
        const int row = bm + wM + mi * 16 + g * 4 + j;
        if (ADD_BIAS)
          ((u16*)Cout)[(long)row * Ncol + col] = f2bf(acc[mi][ni][j] + badd);
        else
          ((float*)Cout)[(long)row * Ncol + col] = acc[mi][ni][j];
      }
    }
  }
}

// ---------------- RoPE + scatter (bf16 qkv in): q->bf16 (pre-scaled), k->cache f32 + bf16 ----------------
__global__ __launch_bounds__(256) void rope_scatter_kernel(const u16* __restrict__ qkvb,
                                                           const int* __restrict__ positions,
                                                           u16* __restrict__ qb,
                                                           u16* __restrict__ kb,
                                                           float* __restrict__ cacheK) {
  const int t = blockIdx.x;
  const int b = t / CS, s = t % CS;
  __shared__ float csv[64], snv[64];
  if (threadIdx.x < 64) {
    const int h = threadIdx.x;
    const float inv = exp2f(-(float)h * (19.931568569324174f / 64.0f)); // 1e6^(-h/64)
    const float fr = (float)positions[t] * inv;
    csv[h] = cosf(fr);
    snv[h] = sinf(fr);
  }
  __syncthreads();
  // fold softmax scale * log2(e) into q so attention scores are exp2-ready
  const float SCQ = 0.08838834764831845f * 1.4426950408889634f;
  const u16* row = qkvb + (long)t * QKVC;
  for (int p = threadIdx.x; p < CN * 64; p += 256) {
    const int n = p >> 6, h = p & 63;
    const float x1 = bf2f(row[n * CH + h]), x2 = bf2f(row[n * CH + h + 64]);
    const float o1 = (x1 * csv[h] - x2 * snv[h]) * SCQ;
    const float o2 = (x2 * csv[h] + x1 * snv[h]) * SCQ;
    const long qi = ((long)(b * CN + n) * CS + s) * CH + h;
    qb[qi] = f2bf(o1);
    qb[qi + 64] = f2bf(o2);
  }
  for (int p = threadIdx.x; p < CK * 64; p += 256) {
    const int kk = p >> 6, h = p & 63;
    const float x1 = bf2f(row[CN * CH + kk * CH + h]), x2 = bf2f(row[CN * CH + kk * CH + h + 64]);
    const float o1 = x1 * csv[h] - x2 * snv[h];
    const float o2 = x2 * csv[h] + x1 * snv[h];
    const long ci = ((long)(b * CS + s) * CK + kk) * CH + h;
    cacheK[ci] = o1;
    cacheK[ci + 64] = o2;
    const long ki = ((long)(b * CK + kk) * CS + s) * CH + h;
    kb[ki] = f2bf(o1);
    kb[ki + 64] = f2bf(o2);
  }
}

// ---------------- V (bf16 qkv in): cache f32 write + transposed bf16 [B][K][H][S] ----------------
__global__ __launch_bounds__(256) void v_transpose_kernel(const u16* __restrict__ qkvb,
                                                          float* __restrict__ cacheV,
                                                          u16* __restrict__ vt) {
  __shared__ float tile[32][33];
  const int s0 = blockIdx.x * 32, h0 = blockIdx.y * 32;
  const int bz = blockIdx.z;                 // b*K + kk
  const int b = bz >> 2, kk = bz & 3;
  const int tx = threadIdx.x, ty = threadIdx.y;
#pragma unroll
  for (int i = ty; i < 32; i += 8) {
    const int s = s0 + i;
    const float v = bf2f(qkvb[(long)(b * CS + s) * QKVC + CN * CH + CK * CH + kk * CH + h0 + tx]);
    cacheV[((long)(b * CS + s) * CK + kk) * CH + h0 + tx] = v;
    tile[i][tx] = v;
  }
  __syncthreads();
#pragma unroll
  for (int i = ty; i < 32; i += 8)
    vt[((long)bz * CH + h0 + i) * CS + s0 + tx] = f2bf(tile[tx][i]);   // exact (already bf16)
}

// ---------------- flash attention: 4 waves x 32 q-rows, 64 kv/step (R9 dbuf version) ----------------
// Double-buffered K/V + counted vmcnt(8); head-major grid (XCD balance); blocked output.
constexpr int PSTR = 72;
__global__ __launch_bounds__(256) void attn_kernel(const u16* __restrict__ qg,
                                                   const u16* __restrict__ kg,
                                                   const u16* __restrict__ vtg,
                                                   u16* __restrict__ og) {
  __shared__ u16 Ks[2][64 * 128];     // K tile [kv][h], 16B chunks XOR-swizzled by (row&7)
  __shared__ u16 Vt[2][128 * 64];     // V^T tile [h][kv], swizzled likewise
  __shared__ u16 Pl[4 * 32 * PSTR];   // per-wave P slab [q][kv0..63]

  const int bn = blockIdx.x;                 // b*N + n  (fast dim -> XCD round-robin)
  const int b = bn / CN, n = bn % CN;
  const int kvh = n / CG;
  const int q0 = ((int)gridDim.y - 1 - (int)blockIdx.y) * 128;  // long blocks first
  const int tid = threadIdx.x;
  const int wid = tid >> 6, lane = tid & 63;
  const int g = lane >> 4, r = lane & 15;
  const int wq0 = q0 + wid * 32;

  short8 qf[2][4];
#pragma unroll
  for (int qt = 0; qt < 2; ++qt) {
    const u16* qrp = qg + ((long)bn * CS + wq0 + qt * 16 + r) * CH;
#pragma unroll
    for (int c = 0; c < 4; ++c) qf[qt][c] = *(const short8*)(qrp + c * 32 + g * 8);
  }

  const u16* kbase = kg + (long)(b * CK + kvh) * CS * CH;   // [S][H]
  const u16* vbase = vtg + (long)(b * CK + kvh) * CH * CS;  // [H][S]

#define STAGE_KV(bufidx, jj) do { \
  _Pragma("unroll") for (int c = 0; c < 4; ++c) { \
    const int pbase = (wid * 4 + c) * 1024; \
    const int pp = pbase + lane * 16; \
    const int row = pp >> 8; \
    const int chl = ((pp >> 4) & 15) ^ (row & 7); \
    gload16(kbase + (long)((jj) + row) * CH + (chl << 3), &Ks[bufidx][pbase >> 1]); \
  } \
  _Pragma("unroll") for (int c = 0; c < 4; ++c) { \
    const int pbase = (wid * 4 + c) * 1024; \
    const int pp = pbase + lane * 16; \
    const int row = pp >> 7; \
    const int chl = ((pp >> 4) & 7) ^ (row & 7); \
    gload16(vbase + (long)row * CS + (jj) + (chl << 3), &Vt[bufidx][pbase >> 1]); \
  } \
} while (0)

  f32x4 oacc[2][8];
#pragma unroll
  for (int qt = 0; qt < 2; ++qt)
#pragma unroll
    for (int c = 0; c < 8; ++c) oacc[qt][c] = f32x4{0.f, 0.f, 0.f, 0.f};
  float m[2] = {-INFINITY, -INFINITY};
  float l[2] = {0.f, 0.f};

  const int nsteps = q0 / 64 + 2;
  STAGE_KV(0, 0);   // prologue: 8 loads in flight
  for (int it = 0; it < nsteps; ++it) {
    const int j0 = it * 64;
    const int cur = it & 1;
    if (it + 1 < nsteps) {
      STAGE_KV(cur ^ 1, j0 + 64);
      asm volatile("s_waitcnt vmcnt(8)" ::: "memory");
    } else {
      asm volatile("s_waitcnt vmcnt(0)" ::: "memory");
    }
    __builtin_amdgcn_s_barrier();

    if (j0 <= wq0 + 31) {
      f32x4 sc[2][4];
#pragma unroll
      for (int qt = 0; qt < 2; ++qt)
#pragma unroll
        for (int kt = 0; kt < 4; ++kt) sc[qt][kt] = f32x4{0.f, 0.f, 0.f, 0.f};
      __builtin_amdgcn_s_setprio(1);
#pragma unroll
      for (int kt = 0; kt < 4; ++kt) {
        short8 kf[4];
#pragma unroll
        for (int c = 0; c < 4; ++c)
          kf[c] = *(const short8*)&Ks[cur][(kt * 16 + r) * 128 + ((((c << 2) + g) ^ (r & 7)) << 3)];
#pragma unroll
        for (int qt = 0; qt < 2; ++qt)
#pragma unroll
          for (int c = 0; c < 4; ++c)
            sc[qt][kt] = __builtin_amdgcn_mfma_f32_16x16x32_bf16(kf[c], qf[qt][c], sc[qt][kt], 0, 0, 0);
      }
      __builtin_amdgcn_s_setprio(0);

      float pmax[2];
#pragma unroll
      for (int qt = 0; qt < 2; ++qt) {
        const int qq = wq0 + qt * 16 + r;
#pragma unroll
        for (int kt = 0; kt < 4; ++kt)
#pragma unroll
          for (int j = 0; j < 4; ++j) {
            const int kv = j0 + kt * 16 + g * 4 + j;
            if (kv > qq) sc[qt][kt][j] = -INFINITY;
          }
        float mx = sc[qt][0][0];
#pragma unroll
        for (int kt = 0; kt < 4; ++kt)
#pragma unroll
          for (int j = 0; j < 4; ++j) mx = fmaxf(mx, sc[qt][kt][j]);
        mx = fmaxf(mx, __shfl_xor(mx, 16));
        mx = fmaxf(mx, __shfl_xor(mx, 32));
        pmax[qt] = mx;
      }

      const bool ok = (pmax[0] <= m[0] + 8.f) && (pmax[1] <= m[1] + 8.f);
      if (!__all(ok)) {
#pragma unroll
        for (int qt = 0; qt < 2; ++qt) {
          const float mn = fmaxf(m[qt], pmax[qt]);
          const float fac = exp2f(m[qt] - mn);
          m[qt] = mn;
          l[qt] *= fac;
#pragma unroll
          for (int j = 0; j < 4; ++j) {
            const float fj = __shfl(fac, g * 4 + j);
#pragma unroll
            for (int c = 0; c < 8; ++c) oacc[qt][c][j] *= fj;
          }
        }
      }

#pragma unroll
      for (int qt = 0; qt < 2; ++qt) {
        float rsum = 0.f;
#pragma unroll
        for (int kt = 0; kt < 4; ++kt) {
          const float p0 = exp2f(sc[qt][kt][0] - m[qt]);
          const float p1 = exp2f(sc[qt][kt][1] - m[qt]);
          const float p2 = exp2f(sc[qt][kt][2] - m[qt]);
          const float p3 = exp2f(sc[qt][kt][3] - m[qt]);
          rsum += (p0 + p1) + (p2 + p3);
          uint2 pk;
          pk.x = (uint32_t)f2bf(p0) | ((uint32_t)f2bf(p1) << 16);
          pk.y = (uint32_t)f2bf(p2) | ((uint32_t)f2bf(p3) << 16);
          *(uint2*)&Pl[wid * 32 * PSTR + (qt * 16 + r) * PSTR + kt * 16 + g * 4] = pk;
        }
        rsum += __shfl_xor(rsum, 16);
        rsum += __shfl_xor(rsum, 32);
        l[qt] += rsum;
      }

      __builtin_amdgcn_s_setprio(1);
#pragma unroll
      for (int ks = 0; ks < 2; ++ks) {
        short8 pfq[2];
#pragma unroll
        for (int qt = 0; qt < 2; ++qt)
          pfq[qt] = *(const short8*)&Pl[wid * 32 * PSTR + (qt * 16 + r) * PSTR + ks * 32 + g * 8];
#pragma unroll
        for (int c = 0; c < 8; ++c) {
          const short8 vf = *(const short8*)&Vt[cur][(c * 16 + r) * 64 + ((((ks << 2) + g) ^ (r & 7)) << 3)];
#pragma unroll
          for (int qt = 0; qt < 2; ++qt)
            oacc[qt][c] = __builtin_amdgcn_mfma_f32_16x16x32_bf16(pfq[qt], vf, oacc[qt][c], 0, 0, 0);
        }
      }
      __builtin_amdgcn_s_setprio(0);
    }

    __builtin_amdgcn_s_barrier();   // protect buf cur from being re-staged next iter
  }
#undef STAGE_KV

  // ---- normalize + write bf16 K-blocked: col = n*128 + c*16 + r ----
#pragma unroll
  for (int qt = 0; qt < 2; ++qt)
#pragma unroll
    for (int j = 0; j < 4; ++j) {
      const float linv = 1.0f / __shfl(l[qt], g * 4 + j);
      const long t = (long)b * CS + wq0 + qt * 16 + g * 4 + j;
#pragma unroll
      for (int c = 0; c < 8; ++c)
        og[((long)(n * 4 + (c >> 1)) * CT + t) * 32 + (c & 1) * 16 + r] = f2bf(oacc[qt][c][j] * linv);
    }
}

// ---------------- host ----------------
extern "C" void kernel_launch(void* const* d_in, const int* in_sizes, int n_in,
                              void* d_out, int out_size, void* d_ws, size_t ws_size,
                              hipStream_t stream) {
  (void)in_sizes; (void)n_in; (void)out_size; (void)ws_size;
  const float* x  = (const float*)d_in[1];
  const int* positions = (const int*)d_in[2];
  const float* Wq = (const float*)d_in[3];
  const float* bq = (const float*)d_in[4];
  const float* Wk = (const float*)d_in[5];
  const float* bk = (const float*)d_in[6];
  const float* Wv = (const float*)d_in[7];
  const float* bv = (const float*)d_in[8];
  const float* Wo = (const float*)d_in[9];
  float* out = (float*)d_out;

  char* ws = (char*)d_ws;
  u16*   xb     = (u16*)(ws + 0L);            // 29,360,128 B  x bf16 blocked [112][T][32]
  u16*   w1t    = (u16*)(ws + 29360128L);     // 33,030,144 B  W_qkv^T bf16 blocked [112][4608][32]
  u16*   wot    = (u16*)(ws + 62390272L);     // 25,690,112 B  Wo^T bf16 blocked [112][3584][32]
  u16*   qkvb   = (u16*)(ws + 88080384L);     // 37,748,736 B  qkv bf16 [T][4608]
  u16*   attn_b = (u16*)(ws + 125829120L);    // 29,360,128 B  attn out bf16 blocked [112][T][32]
  u16*   qb     = (u16*)(ws + 163577856L);    // 29,360,128 B  q roped bf16 [B][N][S][H]
  u16*   kb2    = (u16*)(ws + 192937984L);    //  4,194,304 B  k roped bf16 [B][K][S][H]
  u16*   vt     = (u16*)(ws + 197132288L);    //  4,194,304 B  V^T bf16 [B][K][H][S]
  // total 201,326,592 B

  cvt_blk_kernel<<<dim3((CT * (long)CD) / 1024), 256, 0, stream>>>(x, xb, (long)CT * CD);
  transpose_cvt_kernel<<<dim3(112, 112), dim3(32, 8), 0, stream>>>(Wq, w1t, CN * CH, 0, QKVC);
  transpose_cvt_kernel<<<dim3(16, 112), dim3(32, 8), 0, stream>>>(Wk, w1t, CK * CH, CN * CH, QKVC);
  transpose_cvt_kernel<<<dim3(16, 112), dim3(32, 8), 0, stream>>>(Wv, w1t, CK * CH, CN * CH + CK * CH, QKVC);
  transpose_cvt_kernel<<<dim3(112, 112), dim3(32, 8), 0, stream>>>(Wo, wot, CD, 0, CD);

  // QKV projection: 8 XCD x 2 bm x 36 bn = 576 blocks of 256x128 (bf16 output)
  gemm256_kernel<1><<<dim3(16 * (QKVC / 128)), 512, 0, stream>>>(xb, w1t, qkvb, bq, bk, bv, QKVC, CD);

  rope_scatter_kernel<<<dim3(CT), 256, 0, stream>>>(qkvb, positions, qb, kb2, out);
  v_transpose_kernel<<<dim3(CS / 32, CH / 32, CB * CK), dim3(32, 8), 0, stream>>>(qkvb, out + KV_HALF, vt);

  attn_kernel<<<dim3(CB * CN, CS / 128), 256, 0, stream>>>(qb, kb2, vt, attn_b);

  // O projection: 8 XCD x 2 bm x 28 bn = 448 blocks of 256x128 (f32 output)
  gemm256_kernel<0><<<dim3(16 * (CD / 128)), 512, 0, stream>>>(attn_b, wot, out + 2 * KV_HALF,
                                                               nullptr, nullptr, nullptr, CD, CD);
}

// Round 19
// 436.714 us; speedup vs baseline: 1.0527x; 1.0091x over previous
//
#include <hip/hip_runtime.h>
#include <stdint.h>

typedef unsigned short u16;
typedef __attribute__((ext_vector_type(8))) short short8;
typedef __attribute__((ext_vector_type(4))) float f32x4;
typedef __attribute__((ext_vector_type(4))) unsigned short u16x4;

constexpr int CB = 4, CS = 1024, CD = 3584, CN = 28, CK = 4, CH = 128, CG = 7;
constexpr int CT = CB * CS;                    // 4096 tokens
constexpr int QKVC = CN * CH + 2 * CK * CH;    // 4608 fused qkv cols
constexpr long KV_HALF = (long)CB * CS * CK * CH; // 2,097,152 floats per cache half

__device__ __forceinline__ u16 f2bf(float f) {
  union { float f; uint32_t u; } c; c.f = f;
  uint32_t u = c.u + 0x7fffu + ((c.u >> 16) & 1);   // RNE to bf16
  return (u16)(u >> 16);
}
__device__ __forceinline__ float bf2f(u16 v) {
  union { uint32_t u; float f; } c; c.u = (uint32_t)v << 16;
  return c.f;
}

// async global->LDS, 16B per lane; LDS dest must be wave-uniform base (+lane*16 implicit)
__device__ __forceinline__ void gload16(const void* g, void* l) {
  __builtin_amdgcn_global_load_lds(
      (const __attribute__((address_space(1))) unsigned int*)(uintptr_t)g,
      (__attribute__((address_space(3))) unsigned int*)(uint32_t)(uintptr_t)l,
      16, 0, 0);
}

// ---------------- f32 [T][D] -> bf16 K-blocked [D/32][T][32] ----------------
__global__ __launch_bounds__(256) void cvt_blk_kernel(const float* __restrict__ in,
                                                      u16* __restrict__ outp, long n) {
  long i = ((long)blockIdx.x * 256 + threadIdx.x) * 4;
  if (i < n) {
    const float4 v = *(const float4*)(in + i);
    const int t = (int)(i / CD), d = (int)(i % CD);
    u16x4 o; o.x = f2bf(v.x); o.y = f2bf(v.y); o.z = f2bf(v.z); o.w = f2bf(v.w);
    *(u16x4*)(outp + ((long)(d >> 5) * CT + t) * 32 + (d & 31)) = o;
  }
}

// ---- transpose f32 src[.][C] -> bf16 K-blocked dst[K/32][RT][32], K = src row dim ----
__global__ __launch_bounds__(256) void transpose_cvt_kernel(const float* __restrict__ src,
                                                            u16* __restrict__ dst,
                                                            int C, int dstOff, int RT) {
  __shared__ float tile[32][33];
  const int c0 = blockIdx.x * 32, r0 = blockIdx.y * 32;
  const int tx = threadIdx.x, ty = threadIdx.y;
#pragma unroll
  for (int i = ty; i < 32; i += 8)
    tile[i][tx] = src[(long)(r0 + i) * C + c0 + tx];
  __syncthreads();
#pragma unroll
  for (int i = ty; i < 32; i += 8)
    dst[((long)(r0 >> 5) * RT + dstOff + c0 + i) * 32 + tx] = f2bf(tile[tx][i]);
}

// ---------------- 256x128 bf16 GEMM, BK=32 DOUBLE-buffered, 48KB LDS -> 3 blocks/CU ----------------
// R7's proven 2-buf pair structure (stage t+1 -> vmcnt(3) -> barrier -> ds_read+MFMA ->
// lgkmcnt(0) -> barrier) on R9's K-blocked contiguous streams + XCD-coop mapping.
// launch_bounds(512,4): min 4 waves/EU -> allocator cap 128 VGPR (kernel uses ~56, no
// spill; R11's disaster was (512,6) capping at 40 VGPR). 48KB x 3 = 144KB <= 160KB LDS.
__device__ __forceinline__ void stage_A(u16* dst, const u16* srcTile, int w, int lane) {
  const int ci0 = (w << 7) + lane;        // 1024 chunks of 16B; 2 per thread
  const int ci1 = ci0 + 64;
  const int l0 = (ci0 & 3) ^ ((ci0 >> 3) & 3);
  const int l1 = (ci1 & 3) ^ ((ci1 >> 3) & 3);
  gload16(srcTile + ((ci0 >> 2) << 5) + (l0 << 3), dst + (w << 10));
  gload16(srcTile + ((ci1 >> 2) << 5) + (l1 << 3), dst + (w << 10) + 512);
}
__device__ __forceinline__ void stage_B(u16* dst, const u16* srcTile, int w, int lane) {
  const int ci = (w << 6) + lane;         // 512 chunks; 1 per thread
  const int l = (ci & 3) ^ ((ci >> 3) & 3);
  gload16(srcTile + ((ci >> 2) << 5) + (l << 3), dst + (w << 9));
}

template <int ADD_BIAS>
__global__ __launch_bounds__(512, 4) void gemm256_kernel(const u16* __restrict__ Ablk,
                                                         const u16* __restrict__ Bblk,
                                                         void* __restrict__ Cout,
                                                         const float* __restrict__ bq,
                                                         const float* __restrict__ bk2,
                                                         const float* __restrict__ bv,
                                                         int Ncol, int Kd) {
  __shared__ u16 Al[2][8192];   // 2 x 16KB
  __shared__ u16 Bl[2][4096];   // 2 x 8KB
  const int tid = threadIdx.x;
  const int w = tid >> 6, lane = tid & 63;
  const int g = lane >> 4, r = lane & 15;
  const int gs = (g ^ ((r >> 1) & 3)) << 3;   // swizzled fragment column (u16 units)
  // XCD-cooperative mapping
  const int xcd = (int)blockIdx.x & 7, c = (int)blockIdx.x >> 3;
  const int bm = ((xcd << 1) + (c & 1)) << 8;
  const int bn = (c >> 1) << 7;
  const int wM = (w >> 1) * 64;   // 4 M-slots
  const int wN = (w & 1) * 64;    // 2 N-slots

  f32x4 acc[4][4];
#pragma unroll
  for (int mi = 0; mi < 4; ++mi)
#pragma unroll
    for (int ni = 0; ni < 4; ++ni) acc[mi][ni] = f32x4{0.f, 0.f, 0.f, 0.f};

#define ATILE(t) (Ablk + ((long)(t) * CT + bm) * 32)
#define BTILE(t) (Bblk + ((long)(t) * Ncol + bn) * 32)
  stage_A(&Al[0][0], ATILE(0), w, lane);
  stage_B(&Bl[0][0], BTILE(0), w, lane);

  const int NT = Kd >> 5;
  for (int t = 0; t < NT; ++t) {
    const int p = t & 1;
    if (t + 1 < NT) {
      stage_A(&Al[p ^ 1][0], ATILE(t + 1), w, lane);
      stage_B(&Bl[p ^ 1][0], BTILE(t + 1), w, lane);
      asm volatile("s_waitcnt vmcnt(3)" ::: "memory");   // tile t's 3 loads landed
    } else {
      asm volatile("s_waitcnt vmcnt(0)" ::: "memory");
    }
    __builtin_amdgcn_s_barrier();
    short8 af[4], bf[4];
#pragma unroll
    for (int mi = 0; mi < 4; ++mi)
      af[mi] = *(const short8*)&Al[p][(wM + mi * 16 + r) * 32 + gs];
#pragma unroll
    for (int ni = 0; ni < 4; ++ni)
      bf[ni] = *(const short8*)&Bl[p][(wN + ni * 16 + r) * 32 + gs];
    __builtin_amdgcn_s_setprio(1);
#pragma unroll
    for (int mi = 0; mi < 4; ++mi)
#pragma unroll
      for (int ni = 0; ni < 4; ++ni)
        acc[mi][ni] = __builtin_amdgcn_mfma_f32_16x16x32_bf16(af[mi], bf[ni], acc[mi][ni], 0, 0, 0);
    __builtin_amdgcn_s_setprio(0);
    asm volatile("s_waitcnt lgkmcnt(0)" ::: "memory");   // reads of buf p retired
    __builtin_amdgcn_s_barrier();                        // before buf p is re-staged
  }
#undef ATILE
#undef BTILE

#pragma unroll
  for (int mi = 0; mi < 4; ++mi) {
#pragma unroll
    for (int ni = 0; ni < 4; ++ni) {
      const int col = bn + wN + ni * 16 + r;
      float badd = 0.f;
      if (ADD_BIAS)
        badd = (col < CN * CH) ? bq[col]
             : (col < CN * CH + CK * CH) ? bk2[col - CN * CH]
                                         : bv[col - CN * CH - CK * CH];
#pragma unroll
      for (int j = 0; j < 4; ++j) {
        const int row = bm + wM + mi * 16 + g * 4 + j;
        if (ADD_BIAS)
          ((u16*)Cout)[(long)row * Ncol + col] = f2bf(acc[mi][ni][j] + badd);
        else
          ((float*)Cout)[(long)row * Ncol + col] = acc[mi][ni][j];
      }
    }
  }
}

// ---------------- RoPE + scatter (bf16 qkv in): q->bf16 (pre-scaled), k->cache f32 + bf16 ----------------
__global__ __launch_bounds__(256) void rope_scatter_kernel(const u16* __restrict__ qkvb,
                                                           const int* __restrict__ positions,
                                                           u16* __restrict__ qb,
                                                           u16* __restrict__ kb,
                                                           float* __restrict__ cacheK) {
  const int t = blockIdx.x;
  const int b = t / CS, s = t % CS;
  __shared__ float csv[64], snv[64];
  if (threadIdx.x < 64) {
    const int h = threadIdx.x;
    const float inv = exp2f(-(float)h * (19.931568569324174f / 64.0f)); // 1e6^(-h/64)
    const float fr = (float)positions[t] * inv;
    csv[h] = cosf(fr);
    snv[h] = sinf(fr);
  }
  __syncthreads();
  // fold softmax scale * log2(e) into q so attention scores are exp2-ready
  const float SCQ = 0.08838834764831845f * 1.4426950408889634f;
  const u16* row = qkvb + (long)t * QKVC;
  for (int p = threadIdx.x; p < CN * 64; p += 256) {
    const int n = p >> 6, h = p & 63;
    const float x1 = bf2f(row[n * CH + h]), x2 = bf2f(row[n * CH + h + 64]);
    const float o1 = (x1 * csv[h] - x2 * snv[h]) * SCQ;
    const float o2 = (x2 * csv[h] + x1 * snv[h]) * SCQ;
    const long qi = ((long)(b * CN + n) * CS + s) * CH + h;
    qb[qi] = f2bf(o1);
    qb[qi + 64] = f2bf(o2);
  }
  for (int p = threadIdx.x; p < CK * 64; p += 256) {
    const int kk = p >> 6, h = p & 63;
    const float x1 = bf2f(row[CN * CH + kk * CH + h]), x2 = bf2f(row[CN * CH + kk * CH + h + 64]);
    const float o1 = x1 * csv[h] - x2 * snv[h];
    const float o2 = x2 * csv[h] + x1 * snv[h];
    const long ci = ((long)(b * CS + s) * CK + kk) * CH + h;
    cacheK[ci] = o1;
    cacheK[ci + 64] = o2;
    const long ki = ((long)(b * CK + kk) * CS + s) * CH + h;
    kb[ki] = f2bf(o1);
    kb[ki + 64] = f2bf(o2);
  }
}

// ---------------- V (bf16 qkv in): cache f32 write + transposed bf16 [B][K][H][S] ----------------
__global__ __launch_bounds__(256) void v_transpose_kernel(const u16* __restrict__ qkvb,
                                                          float* __restrict__ cacheV,
                                                          u16* __restrict__ vt) {
  __shared__ float tile[32][33];
  const int s0 = blockIdx.x * 32, h0 = blockIdx.y * 32;
  const int bz = blockIdx.z;                 // b*K + kk
  const int b = bz >> 2, kk = bz & 3;
  const int tx = threadIdx.x, ty = threadIdx.y;
#pragma unroll
  for (int i = ty; i < 32; i += 8) {
    const int s = s0 + i;
    const float v = bf2f(qkvb[(long)(b * CS + s) * QKVC + CN * CH + CK * CH + kk * CH + h0 + tx]);
    cacheV[((long)(b * CS + s) * CK + kk) * CH + h0 + tx] = v;
    tile[i][tx] = v;
  }
  __syncthreads();
#pragma unroll
  for (int i = ty; i < 32; i += 8)
    vt[((long)bz * CH + h0 + i) * CS + s0 + tx] = f2bf(tile[tx][i]);   // exact (already bf16)
}

// ---------------- flash attention: 4 waves x 32 q-rows, 64 kv/step (R9 dbuf version) ----------------
// Double-buffered K/V + counted vmcnt(8); head-major grid (XCD balance); blocked output.
constexpr int PSTR = 72;
__global__ __launch_bounds__(256) void attn_kernel(const u16* __restrict__ qg,
                                                   const u16* __restrict__ kg,
                                                   const u16* __restrict__ vtg,
                                                   u16* __restrict__ og) {
  __shared__ u16 Ks[2][64 * 128];     // K tile [kv][h], 16B chunks XOR-swizzled by (row&7)
  __shared__ u16 Vt[2][128 * 64];     // V^T tile [h][kv], swizzled likewise
  __shared__ u16 Pl[4 * 32 * PSTR];   // per-wave P slab [q][kv0..63]

  const int bn = blockIdx.x;                 // b*N + n  (fast dim -> XCD round-robin)
  const int b = bn / CN, n = bn % CN;
  const int kvh = n / CG;
  const int q0 = ((int)gridDim.y - 1 - (int)blockIdx.y) * 128;  // long blocks first
  const int tid = threadIdx.x;
  const int wid = tid >> 6, lane = tid & 63;
  const int g = lane >> 4, r = lane & 15;
  const int wq0 = q0 + wid * 32;

  short8 qf[2][4];
#pragma unroll
  for (int qt = 0; qt < 2; ++qt) {
    const u16* qrp = qg + ((long)bn * CS + wq0 + qt * 16 + r) * CH;
#pragma unroll
    for (int c = 0; c < 4; ++c) qf[qt][c] = *(const short8*)(qrp + c * 32 + g * 8);
  }

  const u16* kbase = kg + (long)(b * CK + kvh) * CS * CH;   // [S][H]
  const u16* vbase = vtg + (long)(b * CK + kvh) * CH * CS;  // [H][S]

#define STAGE_KV(bufidx, jj) do { \
  _Pragma("unroll") for (int c = 0; c < 4; ++c) { \
    const int pbase = (wid * 4 + c) * 1024; \
    const int pp = pbase + lane * 16; \
    const int row = pp >> 8; \
    const int chl = ((pp >> 4) & 15) ^ (row & 7); \
    gload16(kbase + (long)((jj) + row) * CH + (chl << 3), &Ks[bufidx][pbase >> 1]); \
  } \
  _Pragma("unroll") for (int c = 0; c < 4; ++c) { \
    const int pbase = (wid * 4 + c) * 1024; \
    const int pp = pbase + lane * 16; \
    const int row = pp >> 7; \
    const int chl = ((pp >> 4) & 7) ^ (row & 7); \
    gload16(vbase + (long)row * CS + (jj) + (chl << 3), &Vt[bufidx][pbase >> 1]); \
  } \
} while (0)

  f32x4 oacc[2][8];
#pragma unroll
  for (int qt = 0; qt < 2; ++qt)
#pragma unroll
    for (int c = 0; c < 8; ++c) oacc[qt][c] = f32x4{0.f, 0.f, 0.f, 0.f};
  float m[2] = {-INFINITY, -INFINITY};
  float l[2] = {0.f, 0.f};

  const int nsteps = q0 / 64 + 2;
  STAGE_KV(0, 0);   // prologue: 8 loads in flight
  for (int it = 0; it < nsteps; ++it) {
    const int j0 = it * 64;
    const int cur = it & 1;
    if (it + 1 < nsteps) {
      STAGE_KV(cur ^ 1, j0 + 64);
      asm volatile("s_waitcnt vmcnt(8)" ::: "memory");
    } else {
      asm volatile("s_waitcnt vmcnt(0)" ::: "memory");
    }
    __builtin_amdgcn_s_barrier();

    if (j0 <= wq0 + 31) {
      f32x4 sc[2][4];
#pragma unroll
      for (int qt = 0; qt < 2; ++qt)
#pragma unroll
        for (int kt = 0; kt < 4; ++kt) sc[qt][kt] = f32x4{0.f, 0.f, 0.f, 0.f};
      __builtin_amdgcn_s_setprio(1);
#pragma unroll
      for (int kt = 0; kt < 4; ++kt) {
        short8 kf[4];
#pragma unroll
        for (int c = 0; c < 4; ++c)
          kf[c] = *(const short8*)&Ks[cur][(kt * 16 + r) * 128 + ((((c << 2) + g) ^ (r & 7)) << 3)];
#pragma unroll
        for (int qt = 0; qt < 2; ++qt)
#pragma unroll
          for (int c = 0; c < 4; ++c)
            sc[qt][kt] = __builtin_amdgcn_mfma_f32_16x16x32_bf16(kf[c], qf[qt][c], sc[qt][kt], 0, 0, 0);
      }
      __builtin_amdgcn_s_setprio(0);

      float pmax[2];
#pragma unroll
      for (int qt = 0; qt < 2; ++qt) {
        const int qq = wq0 + qt * 16 + r;
#pragma unroll
        for (int kt = 0; kt < 4; ++kt)
#pragma unroll
          for (int j = 0; j < 4; ++j) {
            const int kv = j0 + kt * 16 + g * 4 + j;
            if (kv > qq) sc[qt][kt][j] = -INFINITY;
          }
        float mx = sc[qt][0][0];
#pragma unroll
        for (int kt = 0; kt < 4; ++kt)
#pragma unroll
          for (int j = 0; j < 4; ++j) mx = fmaxf(mx, sc[qt][kt][j]);
        mx = fmaxf(mx, __shfl_xor(mx, 16));
        mx = fmaxf(mx, __shfl_xor(mx, 32));
        pmax[qt] = mx;
      }

      const bool ok = (pmax[0] <= m[0] + 8.f) && (pmax[1] <= m[1] + 8.f);
      if (!__all(ok)) {
#pragma unroll
        for (int qt = 0; qt < 2; ++qt) {
          const float mn = fmaxf(m[qt], pmax[qt]);
          const float fac = exp2f(m[qt] - mn);
          m[qt] = mn;
          l[qt] *= fac;
#pragma unroll
          for (int j = 0; j < 4; ++j) {
            const float fj = __shfl(fac, g * 4 + j);
#pragma unroll
            for (int c = 0; c < 8; ++c) oacc[qt][c][j] *= fj;
          }
        }
      }

#pragma unroll
      for (int qt = 0; qt < 2; ++qt) {
        float rsum = 0.f;
#pragma unroll
        for (int kt = 0; kt < 4; ++kt) {
          const float p0 = exp2f(sc[qt][kt][0] - m[qt]);
          const float p1 = exp2f(sc[qt][kt][1] - m[qt]);
          const float p2 = exp2f(sc[qt][kt][2] - m[qt]);
          const float p3 = exp2f(sc[qt][kt][3] - m[qt]);
          rsum += (p0 + p1) + (p2 + p3);
          uint2 pk;
          pk.x = (uint32_t)f2bf(p0) | ((uint32_t)f2bf(p1) << 16);
          pk.y = (uint32_t)f2bf(p2) | ((uint32_t)f2bf(p3) << 16);
          *(uint2*)&Pl[wid * 32 * PSTR + (qt * 16 + r) * PSTR + kt * 16 + g * 4] = pk;
        }
        rsum += __shfl_xor(rsum, 16);
        rsum += __shfl_xor(rsum, 32);
        l[qt] += rsum;
      }

      __builtin_amdgcn_s_setprio(1);
#pragma unroll
      for (int ks = 0; ks < 2; ++ks) {
        short8 pfq[2];
#pragma unroll
        for (int qt = 0; qt < 2; ++qt)
          pfq[qt] = *(const short8*)&Pl[wid * 32 * PSTR + (qt * 16 + r) * PSTR + ks * 32 + g * 8];
#pragma unroll
        for (int c = 0; c < 8; ++c) {
          const short8 vf = *(const short8*)&Vt[cur][(c * 16 + r) * 64 + ((((ks << 2) + g) ^ (r & 7)) << 3)];
#pragma unroll
          for (int qt = 0; qt < 2; ++qt)
            oacc[qt][c] = __builtin_amdgcn_mfma_f32_16x16x32_bf16(pfq[qt], vf, oacc[qt][c], 0, 0, 0);
        }
      }
      __builtin_amdgcn_s_setprio(0);
    }

    __builtin_amdgcn_s_barrier();   // protect buf cur from being re-staged next iter
  }
#undef STAGE_KV

  // ---- normalize + write bf16 K-blocked: col = n*128 + c*16 + r ----
#pragma unroll
  for (int qt = 0; qt < 2; ++qt)
#pragma unroll
    for (int j = 0; j < 4; ++j) {
      const float linv = 1.0f / __shfl(l[qt], g * 4 + j);
      const long t = (long)b * CS + wq0 + qt * 16 + g * 4 + j;
#pragma unroll
      for (int c = 0; c < 8; ++c)
        og[((long)(n * 4 + (c >> 1)) * CT + t) * 32 + (c & 1) * 16 + r] = f2bf(oacc[qt][c][j] * linv);
    }
}

// ---------------- host ----------------
extern "C" void kernel_launch(void* const* d_in, const int* in_sizes, int n_in,
                              void* d_out, int out_size, void* d_ws, size_t ws_size,
                              hipStream_t stream) {
  (void)in_sizes; (void)n_in; (void)out_size; (void)ws_size;
  const float* x  = (const float*)d_in[1];
  const int* positions = (const int*)d_in[2];
  const float* Wq = (const float*)d_in[3];
  const float* bq = (const float*)d_in[4];
  const float* Wk = (const float*)d_in[5];
  const float* bk = (const float*)d_in[6];
  const float* Wv = (const float*)d_in[7];
  const float* bv = (const float*)d_in[8];
  const float* Wo = (const float*)d_in[9];
  float* out = (float*)d_out;

  char* ws = (char*)d_ws;
  u16*   xb     = (u16*)(ws + 0L);            // 29,360,128 B  x bf16 blocked [112][T][32]
  u16*   w1t    = (u16*)(ws + 29360128L);     // 33,030,144 B  W_qkv^T bf16 blocked [112][4608][32]
  u16*   wot    = (u16*)(ws + 62390272L);     // 25,690,112 B  Wo^T bf16 blocked [112][3584][32]
  u16*   qkvb   = (u16*)(ws + 88080384L);     // 37,748,736 B  qkv bf16 [T][4608]
  u16*   attn_b = (u16*)(ws + 125829120L);    // 29,360,128 B  attn out bf16 blocked [112][T][32]
  u16*   qb     = (u16*)(ws + 163577856L);    // 29,360,128 B  q roped bf16 [B][N][S][H]
  u16*   kb2    = (u16*)(ws + 192937984L);    //  4,194,304 B  k roped bf16 [B][K][S][H]
  u16*   vt     = (u16*)(ws + 197132288L);    //  4,194,304 B  V^T bf16 [B][K][H][S]
  // total 201,326,592 B

  cvt_blk_kernel<<<dim3((CT * (long)CD) / 1024), 256, 0, stream>>>(x, xb, (long)CT * CD);
  transpose_cvt_kernel<<<dim3(112, 112), dim3(32, 8), 0, stream>>>(Wq, w1t, CN * CH, 0, QKVC);
  transpose_cvt_kernel<<<dim3(16, 112), dim3(32, 8), 0, stream>>>(Wk, w1t, CK * CH, CN * CH, QKVC);
  transpose_cvt_kernel<<<dim3(16, 112), dim3(32, 8), 0, stream>>>(Wv, w1t, CK * CH, CN * CH + CK * CH, QKVC);
  transpose_cvt_kernel<<<dim3(112, 112), dim3(32, 8), 0, stream>>>(Wo, wot, CD, 0, CD);

  // QKV projection: 8 XCD x 2 bm x 36 bn = 576 blocks of 256x128 (bf16 output; single round at 3/CU)
  gemm256_kernel<1><<<dim3(16 * (QKVC / 128)), 512, 0, stream>>>(xb, w1t, qkvb, bq, bk, bv, QKVC, CD);

  rope_scatter_kernel<<<dim3(CT), 256, 0, stream>>>(qkvb, positions, qb, kb2, out);
  v_transpose_kernel<<<dim3(CS / 32, CH / 32, CB * CK), dim3(32, 8), 0, stream>>>(qkvb, out + KV_HALF, vt);

  attn_kernel<<<dim3(CB * CN, CS / 128), 256, 0, stream>>>(qb, kb2, vt, attn_b);

  // O projection: 8 XCD x 2 bm x 28 bn = 448 blocks of 256x128 (f32 output)
  gemm256_kernel<0><<<dim3(16 * (CD / 128)), 512, 0, stream>>>(attn_b, wot, out + 2 * KV_HALF,
                                                               nullptr, nullptr, nullptr, CD, CD);
}

// Round 20
// 434.667 us; speedup vs baseline: 1.0576x; 1.0047x over previous
//
#include <hip/hip_runtime.h>
#include <stdint.h>

typedef unsigned short u16;
typedef __attribute__((ext_vector_type(8))) short short8;
typedef __attribute__((ext_vector_type(4))) float f32x4;
typedef __attribute__((ext_vector_type(4))) unsigned short u16x4;

constexpr int CB = 4, CS = 1024, CD = 3584, CN = 28, CK = 4, CH = 128, CG = 7;
constexpr int CT = CB * CS;                    // 4096 tokens
constexpr int QKVC = CN * CH + 2 * CK * CH;    // 4608 fused qkv cols
constexpr long KV_HALF = (long)CB * CS * CK * CH; // 2,097,152 floats per cache half

__device__ __forceinline__ u16 f2bf(float f) {
  union { float f; uint32_t u; } c; c.f = f;
  uint32_t u = c.u + 0x7fffu + ((c.u >> 16) & 1);   // RNE to bf16
  return (u16)(u >> 16);
}
__device__ __forceinline__ float bf2f(u16 v) {
  union { uint32_t u; float f; } c; c.u = (uint32_t)v << 16;
  return c.f;
}

// async global->LDS, 16B per lane; LDS dest must be wave-uniform base (+lane*16 implicit)
__device__ __forceinline__ void gload16(const void* g, void* l) {
  __builtin_amdgcn_global_load_lds(
      (const __attribute__((address_space(1))) unsigned int*)(uintptr_t)g,
      (__attribute__((address_space(3))) unsigned int*)(uint32_t)(uintptr_t)l,
      16, 0, 0);
}

// ---------------- f32 [T][D] -> bf16 K-blocked [D/32][T][32] ----------------
__global__ __launch_bounds__(256) void cvt_blk_kernel(const float* __restrict__ in,
                                                      u16* __restrict__ outp, long n) {
  long i = ((long)blockIdx.x * 256 + threadIdx.x) * 4;
  if (i < n) {
    const float4 v = *(const float4*)(in + i);
    const int t = (int)(i / CD), d = (int)(i % CD);
    u16x4 o; o.x = f2bf(v.x); o.y = f2bf(v.y); o.z = f2bf(v.z); o.w = f2bf(v.w);
    *(u16x4*)(outp + ((long)(d >> 5) * CT + t) * 32 + (d & 31)) = o;
  }
}

// ---- transpose f32 src[.][C] -> bf16 K-blocked dst[K/32][RT][32], K = src row dim ----
__global__ __launch_bounds__(256) void transpose_cvt_kernel(const float* __restrict__ src,
                                                            u16* __restrict__ dst,
                                                            int C, int dstOff, int RT) {
  __shared__ float tile[32][33];
  const int c0 = blockIdx.x * 32, r0 = blockIdx.y * 32;
  const int tx = threadIdx.x, ty = threadIdx.y;
#pragma unroll
  for (int i = ty; i < 32; i += 8)
    tile[i][tx] = src[(long)(r0 + i) * C + c0 + tx];
  __syncthreads();
#pragma unroll
  for (int i = ty; i < 32; i += 8)
    dst[((long)(r0 >> 5) * RT + dstOff + c0 + i) * 32 + tx] = f2bf(tile[tx][i]);
}

// ---------------- 256x128 bf16 GEMM, BK=32 DOUBLE-buffered, 48KB LDS -> 3 blocks/CU ----------------
// R7's 2-buf pair structure on R9's K-blocked streams + XCD-coop mapping.
// launch_bounds(512,4): min 4 waves/EU -> 128 VGPR cap (kernel uses ~56, no spill).
__device__ __forceinline__ void stage_A(u16* dst, const u16* srcTile, int w, int lane) {
  const int ci0 = (w << 7) + lane;        // 1024 chunks of 16B; 2 per thread
  const int ci1 = ci0 + 64;
  const int l0 = (ci0 & 3) ^ ((ci0 >> 3) & 3);
  const int l1 = (ci1 & 3) ^ ((ci1 >> 3) & 3);
  gload16(srcTile + ((ci0 >> 2) << 5) + (l0 << 3), dst + (w << 10));
  gload16(srcTile + ((ci1 >> 2) << 5) + (l1 << 3), dst + (w << 10) + 512);
}
__device__ __forceinline__ void stage_B(u16* dst, const u16* srcTile, int w, int lane) {
  const int ci = (w << 6) + lane;         // 512 chunks; 1 per thread
  const int l = (ci & 3) ^ ((ci >> 3) & 3);
  gload16(srcTile + ((ci >> 2) << 5) + (l << 3), dst + (w << 9));
}

template <int ADD_BIAS>
__global__ __launch_bounds__(512, 4) void gemm256_kernel(const u16* __restrict__ Ablk,
                                                         const u16* __restrict__ Bblk,
                                                         void* __restrict__ Cout,
                                                         const float* __restrict__ bq,
                                                         const float* __restrict__ bk2,
                                                         const float* __restrict__ bv,
                                                         int Ncol, int Kd) {
  __shared__ u16 Al[2][8192];   // 2 x 16KB
  __shared__ u16 Bl[2][4096];   // 2 x 8KB
  const int tid = threadIdx.x;
  const int w = tid >> 6, lane = tid & 63;
  const int g = lane >> 4, r = lane & 15;
  const int gs = (g ^ ((r >> 1) & 3)) << 3;   // swizzled fragment column (u16 units)
  // XCD-cooperative mapping
  const int xcd = (int)blockIdx.x & 7, c = (int)blockIdx.x >> 3;
  const int bm = ((xcd << 1) + (c & 1)) << 8;
  const int bn = (c >> 1) << 7;
  const int wM = (w >> 1) * 64;   // 4 M-slots
  const int wN = (w & 1) * 64;    // 2 N-slots

  f32x4 acc[4][4];
#pragma unroll
  for (int mi = 0; mi < 4; ++mi)
#pragma unroll
    for (int ni = 0; ni < 4; ++ni) acc[mi][ni] = f32x4{0.f, 0.f, 0.f, 0.f};

#define ATILE(t) (Ablk + ((long)(t) * CT + bm) * 32)
#define BTILE(t) (Bblk + ((long)(t) * Ncol + bn) * 32)
  stage_A(&Al[0][0], ATILE(0), w, lane);
  stage_B(&Bl[0][0], BTILE(0), w, lane);

  const int NT = Kd >> 5;
  for (int t = 0; t < NT; ++t) {
    const int p = t & 1;
    if (t + 1 < NT) {
      stage_A(&Al[p ^ 1][0], ATILE(t + 1), w, lane);
      stage_B(&Bl[p ^ 1][0], BTILE(t + 1), w, lane);
      asm volatile("s_waitcnt vmcnt(3)" ::: "memory");   // tile t's 3 loads landed
    } else {
      asm volatile("s_waitcnt vmcnt(0)" ::: "memory");
    }
    __builtin_amdgcn_s_barrier();
    short8 af[4], bf[4];
#pragma unroll
    for (int mi = 0; mi < 4; ++mi)
      af[mi] = *(const short8*)&Al[p][(wM + mi * 16 + r) * 32 + gs];
#pragma unroll
    for (int ni = 0; ni < 4; ++ni)
      bf[ni] = *(const short8*)&Bl[p][(wN + ni * 16 + r) * 32 + gs];
    __builtin_amdgcn_s_setprio(1);
#pragma unroll
    for (int mi = 0; mi < 4; ++mi)
#pragma unroll
      for (int ni = 0; ni < 4; ++ni)
        acc[mi][ni] = __builtin_amdgcn_mfma_f32_16x16x32_bf16(af[mi], bf[ni], acc[mi][ni], 0, 0, 0);
    __builtin_amdgcn_s_setprio(0);
    asm volatile("s_waitcnt lgkmcnt(0)" ::: "memory");   // reads of buf p retired
    __builtin_amdgcn_s_barrier();                        // before buf p is re-staged
  }
#undef ATILE
#undef BTILE

#pragma unroll
  for (int mi = 0; mi < 4; ++mi) {
#pragma unroll
    for (int ni = 0; ni < 4; ++ni) {
      const int col = bn + wN + ni * 16 + r;
      float badd = 0.f;
      if (ADD_BIAS)
        badd = (col < CN * CH) ? bq[col]
             : (col < CN * CH + CK * CH) ? bk2[col - CN * CH]
                                         : bv[col - CN * CH - CK * CH];
#pragma unroll
      for (int j = 0; j < 4; ++j) {
        const int row = bm + wM + mi * 16 + g * 4 + j;
        if (ADD_BIAS)
          ((u16*)Cout)[(long)row * Ncol + col] = f2bf(acc[mi][ni][j] + badd);
        else
          ((float*)Cout)[(long)row * Ncol + col] = acc[mi][ni][j];
      }
    }
  }
}

// ---------------- RoPE + scatter (bf16 qkv in, x4-vectorized) ----------------
// q -> bf16 (pre-scaled) [B][N][S][H]; k -> cache f32 + bf16 [B][K][S][H].
// Each thread handles 4 consecutive h of one head: u16x4 loads of the (h, h+64)
// pair rows, u16x4 / float4 stores (h0 % 4 == 0 and bases % 128 -> 8/16B aligned).
__global__ __launch_bounds__(256) void rope_scatter_kernel(const u16* __restrict__ qkvb,
                                                           const int* __restrict__ positions,
                                                           u16* __restrict__ qb,
                                                           u16* __restrict__ kb,
                                                           float* __restrict__ cacheK) {
  const int t = blockIdx.x;
  const int b = t / CS, s = t % CS;
  __shared__ float csv[64], snv[64];
  if (threadIdx.x < 64) {
    const int h = threadIdx.x;
    const float inv = exp2f(-(float)h * (19.931568569324174f / 64.0f)); // 1e6^(-h/64)
    const float fr = (float)positions[t] * inv;
    csv[h] = cosf(fr);
    snv[h] = sinf(fr);
  }
  __syncthreads();
  // fold softmax scale * log2(e) into q so attention scores are exp2-ready
  const float SCQ = 0.08838834764831845f * 1.4426950408889634f;
  const u16* row = qkvb + (long)t * QKVC;
  // ---- q heads: CN*16 = 448 vec4 groups ----
  for (int p = threadIdx.x; p < CN * 16; p += 256) {
    const int n = p >> 4, h0 = (p & 15) * 4;
    const u16x4 a = *(const u16x4*)(row + n * CH + h0);
    const u16x4 bv4 = *(const u16x4*)(row + n * CH + h0 + 64);
    u16x4 o1, o2;
#pragma unroll
    for (int ii = 0; ii < 4; ++ii) {
      const float x1 = bf2f(a[ii]), x2 = bf2f(bv4[ii]);
      const float cs = csv[h0 + ii], sn = snv[h0 + ii];
      o1[ii] = f2bf((x1 * cs - x2 * sn) * SCQ);
      o2[ii] = f2bf((x2 * cs + x1 * sn) * SCQ);
    }
    const long qi = ((long)(b * CN + n) * CS + s) * CH + h0;
    *(u16x4*)(qb + qi) = o1;
    *(u16x4*)(qb + qi + 64) = o2;
  }
  // ---- k heads: CK*16 = 64 vec4 groups ----
  for (int p = threadIdx.x; p < CK * 16; p += 256) {
    const int kk = p >> 4, h0 = (p & 15) * 4;
    const u16x4 a = *(const u16x4*)(row + CN * CH + kk * CH + h0);
    const u16x4 bv4 = *(const u16x4*)(row + CN * CH + kk * CH + h0 + 64);
    float4 c1, c2;
    u16x4 o1, o2;
#pragma unroll
    for (int ii = 0; ii < 4; ++ii) {
      const float x1 = bf2f(a[ii]), x2 = bf2f(bv4[ii]);
      const float cs = csv[h0 + ii], sn = snv[h0 + ii];
      const float v1 = x1 * cs - x2 * sn;
      const float v2 = x2 * cs + x1 * sn;
      (&c1.x)[ii] = v1; (&c2.x)[ii] = v2;
      o1[ii] = f2bf(v1); o2[ii] = f2bf(v2);
    }
    const long ci = ((long)(b * CS + s) * CK + kk) * CH + h0;
    *(float4*)(cacheK + ci) = c1;
    *(float4*)(cacheK + ci + 64) = c2;
    const long ki = ((long)(b * CK + kk) * CS + s) * CH + h0;
    *(u16x4*)(kb + ki) = o1;
    *(u16x4*)(kb + ki + 64) = o2;
  }
}

// ---------------- V (bf16 qkv in): cache f32 write + transposed bf16 [B][K][H][S] ----------------
__global__ __launch_bounds__(256) void v_transpose_kernel(const u16* __restrict__ qkvb,
                                                          float* __restrict__ cacheV,
                                                          u16* __restrict__ vt) {
  __shared__ float tile[32][33];
  const int s0 = blockIdx.x * 32, h0 = blockIdx.y * 32;
  const int bz = blockIdx.z;                 // b*K + kk
  const int b = bz >> 2, kk = bz & 3;
  const int tx = threadIdx.x, ty = threadIdx.y;
#pragma unroll
  for (int i = ty; i < 32; i += 8) {
    const int s = s0 + i;
    const float v = bf2f(qkvb[(long)(b * CS + s) * QKVC + CN * CH + CK * CH + kk * CH + h0 + tx]);
    cacheV[((long)(b * CS + s) * CK + kk) * CH + h0 + tx] = v;
    tile[i][tx] = v;
  }
  __syncthreads();
#pragma unroll
  for (int i = ty; i < 32; i += 8)
    vt[((long)bz * CH + h0 + i) * CS + s0 + tx] = f2bf(tile[tx][i]);   // exact (already bf16)
}

// ---------------- flash attention: 4 waves x 32 q-rows, 64 kv/step (R9 dbuf version) ----------------
// Double-buffered K/V + counted vmcnt(8); head-major grid (XCD balance); blocked output.
constexpr int PSTR = 72;
__global__ __launch_bounds__(256) void attn_kernel(const u16* __restrict__ qg,
                                                   const u16* __restrict__ kg,
                                                   const u16* __restrict__ vtg,
                                                   u16* __restrict__ og) {
  __shared__ u16 Ks[2][64 * 128];     // K tile [kv][h], 16B chunks XOR-swizzled by (row&7)
  __shared__ u16 Vt[2][128 * 64];     // V^T tile [h][kv], swizzled likewise
  __shared__ u16 Pl[4 * 32 * PSTR];   // per-wave P slab [q][kv0..63]

  const int bn = blockIdx.x;                 // b*N + n  (fast dim -> XCD round-robin)
  const int b = bn / CN, n = bn % CN;
  const int kvh = n / CG;
  const int q0 = ((int)gridDim.y - 1 - (int)blockIdx.y) * 128;  // long blocks first
  const int tid = threadIdx.x;
  const int wid = tid >> 6, lane = tid & 63;
  const int g = lane >> 4, r = lane & 15;
  const int wq0 = q0 + wid * 32;

  short8 qf[2][4];
#pragma unroll
  for (int qt = 0; qt < 2; ++qt) {
    const u16* qrp = qg + ((long)bn * CS + wq0 + qt * 16 + r) * CH;
#pragma unroll
    for (int c = 0; c < 4; ++c) qf[qt][c] = *(const short8*)(qrp + c * 32 + g * 8);
  }

  const u16* kbase = kg + (long)(b * CK + kvh) * CS * CH;   // [S][H]
  const u16* vbase = vtg + (long)(b * CK + kvh) * CH * CS;  // [H][S]

#define STAGE_KV(bufidx, jj) do { \
  _Pragma("unroll") for (int c = 0; c < 4; ++c) { \
    const int pbase = (wid * 4 + c) * 1024; \
    const int pp = pbase + lane * 16; \
    const int row = pp >> 8; \
    const int chl = ((pp >> 4) & 15) ^ (row & 7); \
    gload16(kbase + (long)((jj) + row) * CH + (chl << 3), &Ks[bufidx][pbase >> 1]); \
  } \
  _Pragma("unroll") for (int c = 0; c < 4; ++c) { \
    const int pbase = (wid * 4 + c) * 1024; \
    const int pp = pbase + lane * 16; \
    const int row = pp >> 7; \
    const int chl = ((pp >> 4) & 7) ^ (row & 7); \
    gload16(vbase + (long)row * CS + (jj) + (chl << 3), &Vt[bufidx][pbase >> 1]); \
  } \
} while (0)

  f32x4 oacc[2][8];
#pragma unroll
  for (int qt = 0; qt < 2; ++qt)
#pragma unroll
    for (int c = 0; c < 8; ++c) oacc[qt][c] = f32x4{0.f, 0.f, 0.f, 0.f};
  float m[2] = {-INFINITY, -INFINITY};
  float l[2] = {0.f, 0.f};

  const int nsteps = q0 / 64 + 2;
  STAGE_KV(0, 0);   // prologue: 8 loads in flight
  for (int it = 0; it < nsteps; ++it) {
    const int j0 = it * 64;
    const int cur = it & 1;
    if (it + 1 < nsteps) {
      STAGE_KV(cur ^ 1, j0 + 64);
      asm volatile("s_waitcnt vmcnt(8)" ::: "memory");
    } else {
      asm volatile("s_waitcnt vmcnt(0)" ::: "memory");
    }
    __builtin_amdgcn_s_barrier();

    if (j0 <= wq0 + 31) {
      f32x4 sc[2][4];
#pragma unroll
      for (int qt = 0; qt < 2; ++qt)
#pragma unroll
        for (int kt = 0; kt < 4; ++kt) sc[qt][kt] = f32x4{0.f, 0.f, 0.f, 0.f};
      __builtin_amdgcn_s_setprio(1);
#pragma unroll
      for (int kt = 0; kt < 4; ++kt) {
        short8 kf[4];
#pragma unroll
        for (int c = 0; c < 4; ++c)
          kf[c] = *(const short8*)&Ks[cur][(kt * 16 + r) * 128 + ((((c << 2) + g) ^ (r & 7)) << 3)];
#pragma unroll
        for (int qt = 0; qt < 2; ++qt)
#pragma unroll
          for (int c = 0; c < 4; ++c)
            sc[qt][kt] = __builtin_amdgcn_mfma_f32_16x16x32_bf16(kf[c], qf[qt][c], sc[qt][kt], 0, 0, 0);
      }
      __builtin_amdgcn_s_setprio(0);

      float pmax[2];
#pragma unroll
      for (int qt = 0; qt < 2; ++qt) {
        const int qq = wq0 + qt * 16 + r;
#pragma unroll
        for (int kt = 0; kt < 4; ++kt)
#pragma unroll
          for (int j = 0; j < 4; ++j) {
            const int kv = j0 + kt * 16 + g * 4 + j;
            if (kv > qq) sc[qt][kt][j] = -INFINITY;
          }
        float mx = sc[qt][0][0];
#pragma unroll
        for (int kt = 0; kt < 4; ++kt)
#pragma unroll
          for (int j = 0; j < 4; ++j) mx = fmaxf(mx, sc[qt][kt][j]);
        mx = fmaxf(mx, __shfl_xor(mx, 16));
        mx = fmaxf(mx, __shfl_xor(mx, 32));
        pmax[qt] = mx;
      }

      const bool ok = (pmax[0] <= m[0] + 8.f) && (pmax[1] <= m[1] + 8.f);
      if (!__all(ok)) {
#pragma unroll
        for (int qt = 0; qt < 2; ++qt) {
          const float mn = fmaxf(m[qt], pmax[qt]);
          const float fac = exp2f(m[qt] - mn);
          m[qt] = mn;
          l[qt] *= fac;
#pragma unroll
          for (int j = 0; j < 4; ++j) {
            const float fj = __shfl(fac, g * 4 + j);
#pragma unroll
            for (int c = 0; c < 8; ++c) oacc[qt][c][j] *= fj;
          }
        }
      }

#pragma unroll
      for (int qt = 0; qt < 2; ++qt) {
        float rsum = 0.f;
#pragma unroll
        for (int kt = 0; kt < 4; ++kt) {
          const float p0 = exp2f(sc[qt][kt][0] - m[qt]);
          const float p1 = exp2f(sc[qt][kt][1] - m[qt]);
          const float p2 = exp2f(sc[qt][kt][2] - m[qt]);
          const float p3 = exp2f(sc[qt][kt][3] - m[qt]);
          rsum += (p0 + p1) + (p2 + p3);
          uint2 pk;
          pk.x = (uint32_t)f2bf(p0) | ((uint32_t)f2bf(p1) << 16);
          pk.y = (uint32_t)f2bf(p2) | ((uint32_t)f2bf(p3) << 16);
          *(uint2*)&Pl[wid * 32 * PSTR + (qt * 16 + r) * PSTR + kt * 16 + g * 4] = pk;
        }
        rsum += __shfl_xor(rsum, 16);
        rsum += __shfl_xor(rsum, 32);
        l[qt] += rsum;
      }

      __builtin_amdgcn_s_setprio(1);
#pragma unroll
      for (int ks = 0; ks < 2; ++ks) {
        short8 pfq[2];
#pragma unroll
        for (int qt = 0; qt < 2; ++qt)
          pfq[qt] = *(const short8*)&Pl[wid * 32 * PSTR + (qt * 16 + r) * PSTR + ks * 32 + g * 8];
#pragma unroll
        for (int c = 0; c < 8; ++c) {
          const short8 vf = *(const short8*)&Vt[cur][(c * 16 + r) * 64 + ((((ks << 2) + g) ^ (r & 7)) << 3)];
#pragma unroll
          for (int qt = 0; qt < 2; ++qt)
            oacc[qt][c] = __builtin_amdgcn_mfma_f32_16x16x32_bf16(pfq[qt], vf, oacc[qt][c], 0, 0, 0);
        }
      }
      __builtin_amdgcn_s_setprio(0);
    }

    __builtin_amdgcn_s_barrier();   // protect buf cur from being re-staged next iter
  }
#undef STAGE_KV

  // ---- normalize + write bf16 K-blocked: col = n*128 + c*16 + r ----
#pragma unroll
  for (int qt = 0; qt < 2; ++qt)
#pragma unroll
    for (int j = 0; j < 4; ++j) {
      const float linv = 1.0f / __shfl(l[qt], g * 4 + j);
      const long t = (long)b * CS + wq0 + qt * 16 + g * 4 + j;
#pragma unroll
      for (int c = 0; c < 8; ++c)
        og[((long)(n * 4 + (c >> 1)) * CT + t) * 32 + (c & 1) * 16 + r] = f2bf(oacc[qt][c][j] * linv);
    }
}

// ---------------- host ----------------
extern "C" void kernel_launch(void* const* d_in, const int* in_sizes, int n_in,
                              void* d_out, int out_size, void* d_ws, size_t ws_size,
                              hipStream_t stream) {
  (void)in_sizes; (void)n_in; (void)out_size; (void)ws_size;
  const float* x  = (const float*)d_in[1];
  const int* positions = (const int*)d_in[2];
  const float* Wq = (const float*)d_in[3];
  const float* bq = (const float*)d_in[4];
  const float* Wk = (const float*)d_in[5];
  const float* bk = (const float*)d_in[6];
  const float* Wv = (const float*)d_in[7];
  const float* bv = (const float*)d_in[8];
  const float* Wo = (const float*)d_in[9];
  float* out = (float*)d_out;

  char* ws = (char*)d_ws;
  u16*   xb     = (u16*)(ws + 0L);            // 29,360,128 B  x bf16 blocked [112][T][32]
  u16*   w1t    = (u16*)(ws + 29360128L);     // 33,030,144 B  W_qkv^T bf16 blocked [112][4608][32]
  u16*   wot    = (u16*)(ws + 62390272L);     // 25,690,112 B  Wo^T bf16 blocked [112][3584][32]
  u16*   qkvb   = (u16*)(ws + 88080384L);     // 37,748,736 B  qkv bf16 [T][4608]
  u16*   attn_b = (u16*)(ws + 125829120L);    // 29,360,128 B  attn out bf16 blocked [112][T][32]
  u16*   qb     = (u16*)(ws + 163577856L);    // 29,360,128 B  q roped bf16 [B][N][S][H]
  u16*   kb2    = (u16*)(ws + 192937984L);    //  4,194,304 B  k roped bf16 [B][K][S][H]
  u16*   vt     = (u16*)(ws + 197132288L);    //  4,194,304 B  V^T bf16 [B][K][H][S]
  // total 201,326,592 B

  cvt_blk_kernel<<<dim3((CT * (long)CD) / 1024), 256, 0, stream>>>(x, xb, (long)CT * CD);
  transpose_cvt_kernel<<<dim3(112, 112), dim3(32, 8), 0, stream>>>(Wq, w1t, CN * CH, 0, QKVC);
  transpose_cvt_kernel<<<dim3(16, 112), dim3(32, 8), 0, stream>>>(Wk, w1t, CK * CH, CN * CH, QKVC);
  transpose_cvt_kernel<<<dim3(16, 112), dim3(32, 8), 0, stream>>>(Wv, w1t, CK * CH, CN * CH + CK * CH, QKVC);
  transpose_cvt_kernel<<<dim3(112, 112), dim3(32, 8), 0, stream>>>(Wo, wot, CD, 0, CD);

  // QKV projection: 8 XCD x 2 bm x 36 bn = 576 blocks of 256x128 (bf16 output; single round at 3/CU)
  gemm256_kernel<1><<<dim3(16 * (QKVC / 128)), 512, 0, stream>>>(xb, w1t, qkvb, bq, bk, bv, QKVC, CD);

  rope_scatter_kernel<<<dim3(CT), 256, 0, stream>>>(qkvb, positions, qb, kb2, out);
  v_transpose_kernel<<<dim3(CS / 32, CH / 32, CB * CK), dim3(32, 8), 0, stream>>>(qkvb, out + KV_HALF, vt);

  attn_kernel<<<dim3(CB * CN, CS / 128), 256, 0, stream>>>(qb, kb2, vt, attn_b);

  // O projection: 8 XCD x 2 bm x 28 bn = 448 blocks of 256x128 (f32 output)
  gemm256_kernel<0><<<dim3(16 * (CD / 128)), 512, 0, stream>>>(attn_b, wot, out + 2 * KV_HALF,
                                                               nullptr, nullptr, nullptr, CD, CD);
}